// Round 4
// baseline (2130.998 us; speedup 1.0000x reference)
//
#include <hip/hip_runtime.h>
#include <math.h>

#define D_MODEL 256
#define D_INNER 512
#define D_STATE 16
#define D_CONV 4
#define DT_RANK 16
#define N_LAYERS 4
#define CITY 300
#define BATCH 32
#define SEQ 300
#define NTOK (BATCH * SEQ)   // 9600
#define CH 10                // scan chunk length (SEQ % CH == 0)

__device__ __forceinline__ float fast_sig(float x) {
    return __builtin_amdgcn_rcpf(1.f + __expf(-x));
}

// ---------------- embedding ----------------
__global__ void embed_kernel(const float* __restrict__ coords,
                             const float* __restrict__ eW,
                             const float* __restrict__ eb,
                             float* __restrict__ x) {
    int t = blockIdx.x, d = threadIdx.x;
    float c0 = coords[t * 2 + 0];
    float c1 = coords[t * 2 + 1];
    x[t * D_MODEL + d] = c0 * eW[d * 2 + 0] + c1 * eW[d * 2 + 1] + eb[d];
}

// ------------- residual add + layernorm -------------
__global__ void ln_res_kernel(const float* __restrict__ xin, float* __restrict__ resid,
                              float* __restrict__ h,
                              const float* __restrict__ w,
                              const float* __restrict__ b, int first) {
    int t = blockIdx.x, d = threadIdx.x;
    float r = xin[t * D_MODEL + d] + (first ? 0.f : resid[t * D_MODEL + d]);
    resid[t * D_MODEL + d] = r;
    __shared__ float s1[D_MODEL], s2[D_MODEL];
    s1[d] = r; s2[d] = r * r;
    __syncthreads();
    for (int off = D_MODEL / 2; off > 0; off >>= 1) {
        if (d < off) { s1[d] += s1[d + off]; s2[d] += s2[d + off]; }
        __syncthreads();
    }
    float mean = s1[0] * (1.f / D_MODEL);
    float var = s2[0] * (1.f / D_MODEL) - mean * mean;
    h[t * D_MODEL + d] = (r - mean) * rsqrtf(var + 1e-5f) * w[d] + b[d];
}

// ------------- final add + RMSNorm -------------
__global__ void final_rms_kernel(const float* __restrict__ xin, const float* __restrict__ resid,
                                 const float* __restrict__ w,
                                 const float* __restrict__ b, float* __restrict__ h) {
    int t = blockIdx.x, d = threadIdx.x;
    float r = xin[t * D_MODEL + d] + resid[t * D_MODEL + d];
    __shared__ float s2[D_MODEL];
    s2[d] = r * r;
    __syncthreads();
    for (int off = D_MODEL / 2; off > 0; off >>= 1) {
        if (d < off) s2[d] += s2[d + off];
        __syncthreads();
    }
    float rms = r * rsqrtf(s2[0] * (1.f / D_MODEL) + 1e-5f);
    h[t * D_MODEL + d] = rms * w[d] + b[d];
}

// ------------- tiled f32 GEMM: C[t,n] = sum_k A[t,k] * W[n,k] -------------
template <int BM, int BN, int TM, int TN, bool GN>
__global__ __launch_bounds__(256, 2) void gemm_tiled(const float* __restrict__ A,
                                                     const float* __restrict__ W,
                                                     float* __restrict__ C, int N, int K) {
    __shared__ float As[16 * BM];
    __shared__ float Bs[16 * BN];
    const int t0 = blockIdx.x * BM;
    const int n0 = blockIdx.y * BN;
    const int tid = threadIdx.x;
    constexpr int MT = BM / TM;
    const int tx = tid % MT, ty = tid / MT;
    const int m0 = tx * TM, nn0 = ty * TN;
    float acc[TM][TN];
#pragma unroll
    for (int i = 0; i < TM; i++)
#pragma unroll
        for (int j = 0; j < TN; j++) acc[i][j] = 0.f;

    for (int k0 = 0; k0 < K; k0 += 16) {
#pragma unroll
        for (int r = 0; r < BM / 64; r++) {
            int s = tid + 256 * r;
            int m = s >> 2, kq = s & 3;
            float4 v = *(const float4*)(A + (size_t)(t0 + m) * K + k0 + kq * 4);
            As[(kq * 4 + 0) * BM + m] = v.x;
            As[(kq * 4 + 1) * BM + m] = v.y;
            As[(kq * 4 + 2) * BM + m] = v.z;
            As[(kq * 4 + 3) * BM + m] = v.w;
        }
#pragma unroll
        for (int r = 0; r < BN / 64; r++) {
            int s = tid + 256 * r;
            int m = s >> 2, kq = s & 3;
            int nrow = n0 + m;
            float4 v = make_float4(0.f, 0.f, 0.f, 0.f);
            if (!GN || nrow < N)
                v = *(const float4*)(W + (size_t)nrow * K + k0 + kq * 4);
            Bs[(kq * 4 + 0) * BN + m] = v.x;
            Bs[(kq * 4 + 1) * BN + m] = v.y;
            Bs[(kq * 4 + 2) * BN + m] = v.z;
            Bs[(kq * 4 + 3) * BN + m] = v.w;
        }
        __syncthreads();
#pragma unroll
        for (int kc = 0; kc < 16; kc++) {
            float a[TM], b[TN];
#pragma unroll
            for (int i4 = 0; i4 < TM / 4; i4++)
                *(float4*)&a[i4 * 4] = *(const float4*)&As[kc * BM + m0 + i4 * 4];
#pragma unroll
            for (int j4 = 0; j4 < TN / 4; j4++)
                *(float4*)&b[j4 * 4] = *(const float4*)&Bs[kc * BN + nn0 + j4 * 4];
#pragma unroll
            for (int i = 0; i < TM; i++)
#pragma unroll
                for (int j = 0; j < TN; j++) acc[i][j] = fmaf(a[i], b[j], acc[i][j]);
        }
        __syncthreads();
    }
#pragma unroll
    for (int i = 0; i < TM; i++) {
        int t = t0 + m0 + i;
#pragma unroll
        for (int j4 = 0; j4 < TN / 4; j4++) {
            int n = n0 + nn0 + j4 * 4;
            if (!GN || n < N)
                *(float4*)(C + (size_t)t * N + n) =
                    make_float4(acc[i][j4 * 4], acc[i][j4 * 4 + 1],
                                acc[i][j4 * 4 + 2], acc[i][j4 * 4 + 3]);
        }
    }
}

// ------------- fused causal conv (k=4) + SiLU + xproj; wave = 2 tokens -------------
__global__ __launch_bounds__(64) void conv_xproj_kernel(
    const float* __restrict__ xz, const float* __restrict__ cW,
    const float* __restrict__ cb, const float* __restrict__ xW,
    float* __restrict__ xc, float* __restrict__ dbl) {
    const int lane = threadIdx.x;
    const int t0 = blockIdx.x * 2;
    const int ch = lane * 8;
    float4 cwv[8];
#pragma unroll
    for (int c = 0; c < 8; c++) cwv[c] = *(const float4*)(cW + (size_t)(ch + c) * 4);
    float4 cb0 = *(const float4*)(cb + ch);
    float4 cb1 = *(const float4*)(cb + ch + 4);
    float cbv[8] = {cb0.x, cb0.y, cb0.z, cb0.w, cb1.x, cb1.y, cb1.z, cb1.w};

    float x8[2][8];
#pragma unroll
    for (int tok = 0; tok < 2; tok++) {
        int t = t0 + tok;
        int l = t % SEQ;
        float accv[8];
#pragma unroll
        for (int c = 0; c < 8; c++) accv[c] = cbv[c];
#pragma unroll
        for (int k = 0; k < D_CONV; k++) {
            int ll = l - 3 + k;
            if (ll >= 0) {
                const float* src = xz + (size_t)(t - 3 + k) * 1024 + ch;
                float4 v0 = *(const float4*)src;
                float4 v1 = *(const float4*)(src + 4);
                float vv[8] = {v0.x, v0.y, v0.z, v0.w, v1.x, v1.y, v1.z, v1.w};
#pragma unroll
                for (int c = 0; c < 8; c++) {
                    float w = (k == 0) ? cwv[c].x : (k == 1) ? cwv[c].y
                             : (k == 2) ? cwv[c].z : cwv[c].w;
                    accv[c] = fmaf(vv[c], w, accv[c]);
                }
            }
        }
#pragma unroll
        for (int c = 0; c < 8; c++) {
            float a = accv[c];
            x8[tok][c] = a * fast_sig(a);
        }
        *(float4*)(xc + (size_t)t * 512 + ch) =
            make_float4(x8[tok][0], x8[tok][1], x8[tok][2], x8[tok][3]);
        *(float4*)(xc + (size_t)t * 512 + ch + 4) =
            make_float4(x8[tok][4], x8[tok][5], x8[tok][6], x8[tok][7]);
    }
    float keep0 = 0.f, keep1 = 0.f;
    for (int j = 0; j < 48; j++) {
        const float* wr = xW + (size_t)j * 512 + ch;
        float4 w0 = *(const float4*)wr;
        float4 w1 = *(const float4*)(wr + 4);
        float ww[8] = {w0.x, w0.y, w0.z, w0.w, w1.x, w1.y, w1.z, w1.w};
        float a0 = 0.f, a1 = 0.f;
#pragma unroll
        for (int c = 0; c < 8; c++) {
            a0 = fmaf(ww[c], x8[0][c], a0);
            a1 = fmaf(ww[c], x8[1][c], a1);
        }
#pragma unroll
        for (int m = 1; m < 64; m <<= 1) {
            a0 += __shfl_xor(a0, m);
            a1 += __shfl_xor(a1, m);
        }
        if (lane == j) { keep0 = a0; keep1 = a1; }
    }
    if (lane < 48) {
        dbl[(size_t)t0 * 48 + lane] = keep0;
        dbl[(size_t)(t0 + 1) * 48 + lane] = keep1;
    }
}

// ------------- SSM scan v3: chunked register prefetch, fused dtproj -------------
// 256 single-wave blocks = 32 batches x 8 d-groups; x/z prefetched CH steps ahead
// into ping-pong register files; dbl row in compile-time ping-pong (SGPR path).
__global__ __launch_bounds__(64) void scan_kernel(
    const float* __restrict__ xc, const float* __restrict__ dbl,
    const float* __restrict__ xz, const float* __restrict__ A_log,
    const float* __restrict__ Dskip, const float* __restrict__ dtW,
    const float* __restrict__ dtb, float* __restrict__ yv) {
    const int b = blockIdx.x >> 3;
    const int d = ((blockIdx.x & 7) << 6) + threadIdx.x;
    const float LOG2E = 1.44269504088896340736f;
    float ArowL2[D_STATE], dWr[DT_RANK];
#pragma unroll
    for (int s4 = 0; s4 < 4; s4++) {
        float4 v = *(const float4*)(A_log + (size_t)d * D_STATE + s4 * 4);
        ArowL2[s4 * 4 + 0] = -__expf(v.x) * LOG2E;
        ArowL2[s4 * 4 + 1] = -__expf(v.y) * LOG2E;
        ArowL2[s4 * 4 + 2] = -__expf(v.z) * LOG2E;
        ArowL2[s4 * 4 + 3] = -__expf(v.w) * LOG2E;
        float4 w = *(const float4*)(dtW + (size_t)d * DT_RANK + s4 * 4);
        dWr[s4 * 4 + 0] = w.x; dWr[s4 * 4 + 1] = w.y;
        dWr[s4 * 4 + 2] = w.z; dWr[s4 * 4 + 3] = w.w;
    }
    const float dtbv = dtb[d], dsk = Dskip[d];
    float h[D_STATE];
#pragma unroll
    for (int s = 0; s < D_STATE; s++) h[s] = 0.f;
    const size_t tb = (size_t)b * SEQ;
    const float* __restrict__ dr = dbl + tb * 48;
    const float* __restrict__ xp = xc + tb * 512 + d;
    const float* __restrict__ zp = xz + tb * 1024 + 512 + d;
    float* __restrict__ yp = yv + tb * 512 + d;

    float xb[2][CH], zb[2][CH];
#pragma unroll
    for (int j = 0; j < CH; j++) {
        xb[0][j] = xp[(size_t)j * 512];
        zb[0][j] = zp[(size_t)j * 1024];
    }
    float db0[48], db1[48];
#pragma unroll
    for (int i = 0; i < 12; i++) ((float4*)db0)[i] = ((const float4*)dr)[i];

    for (int c = 0; c < SEQ / CH; c++) {
        const int cb_ = c & 1, nb_ = cb_ ^ 1;
        const int l0 = c * CH;
        // prefetch next chunk's x/z (clamped; values unused on last chunk)
        int lbase = l0 + CH;
#pragma unroll
        for (int j = 0; j < CH; j++) {
            int l = lbase + j; l = (l > SEQ - 1) ? (SEQ - 1) : l;
            xb[nb_][j] = xp[(size_t)l * 512];
            zb[nb_][j] = zp[(size_t)l * 1024];
        }
#pragma unroll
        for (int j = 0; j < CH; j++) {
            int l = l0 + j;
            float* cur = (j & 1) ? db1 : db0;
            float* nxtb = (j & 1) ? db0 : db1;
            {   // prefetch dbl row l+1 (clamped)
                int ln = l + 1; ln = (ln > SEQ - 1) ? (SEQ - 1) : ln;
                const float4* nr = (const float4*)(dr + (size_t)ln * 48);
#pragma unroll
                for (int i = 0; i < 12; i++) ((float4*)nxtb)[i] = nr[i];
            }
            // dt = softplus(cur[0:16] . dWr + b)  (4-way tree)
            float a0 = dtbv, a1 = 0.f, a2 = 0.f, a3 = 0.f;
#pragma unroll
            for (int r = 0; r < 4; r++) {
                a0 = fmaf(cur[r], dWr[r], a0);
                a1 = fmaf(cur[4 + r], dWr[4 + r], a1);
                a2 = fmaf(cur[8 + r], dWr[8 + r], a2);
                a3 = fmaf(cur[12 + r], dWr[12 + r], a3);
            }
            float acc = (a0 + a1) + (a2 + a3);
            float dtt = fmaxf(acc, 0.f) + __logf(1.f + __expf(-fabsf(acc)));
            float xv = xb[cb_][j], zv = zb[cb_][j];
            float dtx = dtt * xv;
            float y0 = 0.f, y1 = 0.f, y2 = 0.f, y3 = 0.f;
#pragma unroll
            for (int s = 0; s < 4; s++) {
                float dA0 = exp2f(dtt * ArowL2[s]);
                float dA1 = exp2f(dtt * ArowL2[4 + s]);
                float dA2 = exp2f(dtt * ArowL2[8 + s]);
                float dA3 = exp2f(dtt * ArowL2[12 + s]);
                h[s] = fmaf(dA0, h[s], dtx * cur[16 + s]);
                h[4 + s] = fmaf(dA1, h[4 + s], dtx * cur[20 + s]);
                h[8 + s] = fmaf(dA2, h[8 + s], dtx * cur[24 + s]);
                h[12 + s] = fmaf(dA3, h[12 + s], dtx * cur[28 + s]);
                y0 = fmaf(h[s], cur[32 + s], y0);
                y1 = fmaf(h[4 + s], cur[36 + s], y1);
                y2 = fmaf(h[8 + s], cur[40 + s], y2);
                y3 = fmaf(h[12 + s], cur[44 + s], y3);
            }
            float y = (y0 + y1) + (y2 + y3);
            yp[(size_t)l * 512] = (y + xv * dsk) * (zv * fast_sig(zv));
        }
    }
}

extern "C" void kernel_launch(void* const* d_in, const int* in_sizes, int n_in,
                              void* d_out, int out_size, void* d_ws, size_t ws_size,
                              hipStream_t stream) {
    const float* coords   = (const float*)d_in[0];
    const float* emb_W    = (const float*)d_in[1];
    const float* emb_b    = (const float*)d_in[2];
    const float* ln_w     = (const float*)d_in[3];
    const float* ln_b     = (const float*)d_in[4];
    const float* in_W     = (const float*)d_in[5];
    const float* conv_W   = (const float*)d_in[6];
    const float* conv_b   = (const float*)d_in[7];
    const float* xproj_W  = (const float*)d_in[8];
    const float* dtproj_W = (const float*)d_in[9];
    const float* dtproj_b = (const float*)d_in[10];
    const float* A_log    = (const float*)d_in[11];
    const float* D_skip   = (const float*)d_in[12];
    const float* out_W    = (const float*)d_in[13];
    const float* normf_w  = (const float*)d_in[14];
    const float* normf_b  = (const float*)d_in[15];
    const float* head_W   = (const float*)d_in[16];
    float* out = (float*)d_out;

    const int T = NTOK;  // 9600
    float* x     = (float*)d_ws;
    float* resid = x + (size_t)T * D_MODEL;
    float* h     = resid + (size_t)T * D_MODEL;
    float* xz    = h + (size_t)T * D_MODEL;
    float* xc    = xz + (size_t)T * 2 * D_INNER;
    float* dbl   = xc + (size_t)T * D_INNER;
    float* yv    = dbl + (size_t)T * 48;

    embed_kernel<<<T, D_MODEL, 0, stream>>>(coords, emb_W, emb_b, x);

    for (int i = 0; i < N_LAYERS; i++) {
        ln_res_kernel<<<T, D_MODEL, 0, stream>>>(x, resid, h, ln_w + i * D_MODEL,
                                                 ln_b + i * D_MODEL, i == 0);
        gemm_tiled<128, 128, 8, 8, false><<<dim3(T / 128, 8), 256, 0, stream>>>(
            h, in_W + (size_t)i * 2 * D_INNER * D_MODEL, xz, 2 * D_INNER, D_MODEL);
        conv_xproj_kernel<<<T / 2, 64, 0, stream>>>(
            xz, conv_W + i * D_INNER * D_CONV, conv_b + i * D_INNER,
            xproj_W + (size_t)i * 48 * D_INNER, xc, dbl);
        scan_kernel<<<BATCH * 8, 64, 0, stream>>>(
            xc, dbl, xz, A_log + (size_t)i * D_INNER * D_STATE, D_skip + i * D_INNER,
            dtproj_W + (size_t)i * D_INNER * DT_RANK, dtproj_b + i * D_INNER, yv);
        gemm_tiled<128, 64, 8, 4, false><<<dim3(T / 128, 4), 256, 0, stream>>>(
            yv, out_W + (size_t)i * D_MODEL * D_INNER, x, D_MODEL, D_INNER);
    }

    final_rms_kernel<<<T, D_MODEL, 0, stream>>>(x, resid, normf_w, normf_b, h);
    gemm_tiled<128, 64, 8, 4, true><<<dim3(T / 128, 5), 256, 0, stream>>>(
        h, head_W, out, CITY, D_MODEL);
}

// Round 5
// 1261.037 us; speedup vs baseline: 1.6899x; 1.6899x over previous
//
#include <hip/hip_runtime.h>
#include <math.h>

#define D_MODEL 256
#define D_INNER 512
#define D_STATE 16
#define D_CONV 4
#define DT_RANK 16
#define N_LAYERS 4
#define CITY 300
#define BATCH 32
#define SEQ 300
#define NTOK (BATCH * SEQ)   // 9600
#define NSEG 10
#define SEGLEN (SEQ / NSEG)  // 30

__device__ __forceinline__ float fast_sig(float x) {
    return __builtin_amdgcn_rcpf(1.f + __expf(-x));
}

// ---------------- embedding ----------------
__global__ void embed_kernel(const float* __restrict__ coords,
                             const float* __restrict__ eW,
                             const float* __restrict__ eb,
                             float* __restrict__ x) {
    int t = blockIdx.x, d = threadIdx.x;
    float c0 = coords[t * 2 + 0];
    float c1 = coords[t * 2 + 1];
    x[t * D_MODEL + d] = c0 * eW[d * 2 + 0] + c1 * eW[d * 2 + 1] + eb[d];
}

// ------------- residual add + layernorm -------------
__global__ void ln_res_kernel(const float* __restrict__ xin, float* __restrict__ resid,
                              float* __restrict__ h,
                              const float* __restrict__ w,
                              const float* __restrict__ b, int first) {
    int t = blockIdx.x, d = threadIdx.x;
    float r = xin[t * D_MODEL + d] + (first ? 0.f : resid[t * D_MODEL + d]);
    resid[t * D_MODEL + d] = r;
    __shared__ float s1[D_MODEL], s2[D_MODEL];
    s1[d] = r; s2[d] = r * r;
    __syncthreads();
    for (int off = D_MODEL / 2; off > 0; off >>= 1) {
        if (d < off) { s1[d] += s1[d + off]; s2[d] += s2[d + off]; }
        __syncthreads();
    }
    float mean = s1[0] * (1.f / D_MODEL);
    float var = s2[0] * (1.f / D_MODEL) - mean * mean;
    h[t * D_MODEL + d] = (r - mean) * rsqrtf(var + 1e-5f) * w[d] + b[d];
}

// ------------- final add + RMSNorm -------------
__global__ void final_rms_kernel(const float* __restrict__ xin, const float* __restrict__ resid,
                                 const float* __restrict__ w,
                                 const float* __restrict__ b, float* __restrict__ h) {
    int t = blockIdx.x, d = threadIdx.x;
    float r = xin[t * D_MODEL + d] + resid[t * D_MODEL + d];
    __shared__ float s2[D_MODEL];
    s2[d] = r * r;
    __syncthreads();
    for (int off = D_MODEL / 2; off > 0; off >>= 1) {
        if (d < off) s2[d] += s2[d + off];
        __syncthreads();
    }
    float rms = r * rsqrtf(s2[0] * (1.f / D_MODEL) + 1e-5f);
    h[t * D_MODEL + d] = rms * w[d] + b[d];
}

// ------------- tiled f32 GEMM: C[t,n] = sum_k A[t,k] * W[n,k] -------------
template <int BM, int BN, int TM, int TN, bool GN>
__global__ __launch_bounds__(256, 2) void gemm_tiled(const float* __restrict__ A,
                                                     const float* __restrict__ W,
                                                     float* __restrict__ C, int N, int K) {
    __shared__ float As[16 * BM];
    __shared__ float Bs[16 * BN];
    const int t0 = blockIdx.x * BM;
    const int n0 = blockIdx.y * BN;
    const int tid = threadIdx.x;
    constexpr int MT = BM / TM;
    const int tx = tid % MT, ty = tid / MT;
    const int m0 = tx * TM, nn0 = ty * TN;
    float acc[TM][TN];
#pragma unroll
    for (int i = 0; i < TM; i++)
#pragma unroll
        for (int j = 0; j < TN; j++) acc[i][j] = 0.f;

    for (int k0 = 0; k0 < K; k0 += 16) {
#pragma unroll
        for (int r = 0; r < BM / 64; r++) {
            int s = tid + 256 * r;
            int m = s >> 2, kq = s & 3;
            float4 v = *(const float4*)(A + (size_t)(t0 + m) * K + k0 + kq * 4);
            As[(kq * 4 + 0) * BM + m] = v.x;
            As[(kq * 4 + 1) * BM + m] = v.y;
            As[(kq * 4 + 2) * BM + m] = v.z;
            As[(kq * 4 + 3) * BM + m] = v.w;
        }
#pragma unroll
        for (int r = 0; r < BN / 64; r++) {
            int s = tid + 256 * r;
            int m = s >> 2, kq = s & 3;
            int nrow = n0 + m;
            float4 v = make_float4(0.f, 0.f, 0.f, 0.f);
            if (!GN || nrow < N)
                v = *(const float4*)(W + (size_t)nrow * K + k0 + kq * 4);
            Bs[(kq * 4 + 0) * BN + m] = v.x;
            Bs[(kq * 4 + 1) * BN + m] = v.y;
            Bs[(kq * 4 + 2) * BN + m] = v.z;
            Bs[(kq * 4 + 3) * BN + m] = v.w;
        }
        __syncthreads();
#pragma unroll
        for (int kc = 0; kc < 16; kc++) {
            float a[TM], b[TN];
#pragma unroll
            for (int i4 = 0; i4 < TM / 4; i4++)
                *(float4*)&a[i4 * 4] = *(const float4*)&As[kc * BM + m0 + i4 * 4];
#pragma unroll
            for (int j4 = 0; j4 < TN / 4; j4++)
                *(float4*)&b[j4 * 4] = *(const float4*)&Bs[kc * BN + nn0 + j4 * 4];
#pragma unroll
            for (int i = 0; i < TM; i++)
#pragma unroll
                for (int j = 0; j < TN; j++) acc[i][j] = fmaf(a[i], b[j], acc[i][j]);
        }
        __syncthreads();
    }
#pragma unroll
    for (int i = 0; i < TM; i++) {
        int t = t0 + m0 + i;
#pragma unroll
        for (int j4 = 0; j4 < TN / 4; j4++) {
            int n = n0 + nn0 + j4 * 4;
            if (!GN || n < N)
                *(float4*)(C + (size_t)t * N + n) =
                    make_float4(acc[i][j4 * 4], acc[i][j4 * 4 + 1],
                                acc[i][j4 * 4 + 2], acc[i][j4 * 4 + 3]);
        }
    }
}

// ------------- fused causal conv (k=4) + SiLU + xproj; wave = 2 tokens -------------
__global__ __launch_bounds__(64) void conv_xproj_kernel(
    const float* __restrict__ xz, const float* __restrict__ cW,
    const float* __restrict__ cb, const float* __restrict__ xW,
    float* __restrict__ xc, float* __restrict__ dbl) {
    const int lane = threadIdx.x;
    const int t0 = blockIdx.x * 2;
    const int ch = lane * 8;
    float4 cwv[8];
#pragma unroll
    for (int c = 0; c < 8; c++) cwv[c] = *(const float4*)(cW + (size_t)(ch + c) * 4);
    float4 cb0 = *(const float4*)(cb + ch);
    float4 cb1 = *(const float4*)(cb + ch + 4);
    float cbv[8] = {cb0.x, cb0.y, cb0.z, cb0.w, cb1.x, cb1.y, cb1.z, cb1.w};

    float x8[2][8];
#pragma unroll
    for (int tok = 0; tok < 2; tok++) {
        int t = t0 + tok;
        int l = t % SEQ;
        float accv[8];
#pragma unroll
        for (int c = 0; c < 8; c++) accv[c] = cbv[c];
#pragma unroll
        for (int k = 0; k < D_CONV; k++) {
            int ll = l - 3 + k;
            if (ll >= 0) {
                const float* src = xz + (size_t)(t - 3 + k) * 1024 + ch;
                float4 v0 = *(const float4*)src;
                float4 v1 = *(const float4*)(src + 4);
                float vv[8] = {v0.x, v0.y, v0.z, v0.w, v1.x, v1.y, v1.z, v1.w};
#pragma unroll
                for (int c = 0; c < 8; c++) {
                    float w = (k == 0) ? cwv[c].x : (k == 1) ? cwv[c].y
                             : (k == 2) ? cwv[c].z : cwv[c].w;
                    accv[c] = fmaf(vv[c], w, accv[c]);
                }
            }
        }
#pragma unroll
        for (int c = 0; c < 8; c++) {
            float a = accv[c];
            x8[tok][c] = a * fast_sig(a);
        }
        *(float4*)(xc + (size_t)t * 512 + ch) =
            make_float4(x8[tok][0], x8[tok][1], x8[tok][2], x8[tok][3]);
        *(float4*)(xc + (size_t)t * 512 + ch + 4) =
            make_float4(x8[tok][4], x8[tok][5], x8[tok][6], x8[tok][7]);
    }
    float keep0 = 0.f, keep1 = 0.f;
    for (int j = 0; j < 48; j++) {
        const float* wr = xW + (size_t)j * 512 + ch;
        float4 w0 = *(const float4*)wr;
        float4 w1 = *(const float4*)(wr + 4);
        float ww[8] = {w0.x, w0.y, w0.z, w0.w, w1.x, w1.y, w1.z, w1.w};
        float a0 = 0.f, a1 = 0.f;
#pragma unroll
        for (int c = 0; c < 8; c++) {
            a0 = fmaf(ww[c], x8[0][c], a0);
            a1 = fmaf(ww[c], x8[1][c], a1);
        }
#pragma unroll
        for (int m = 1; m < 64; m <<= 1) {
            a0 += __shfl_xor(a0, m);
            a1 += __shfl_xor(a1, m);
        }
        if (lane == j) { keep0 = a0; keep1 = a1; }
    }
    if (lane < 48) {
        dbl[(size_t)t0 * 48 + lane] = keep0;
        dbl[(size_t)(t0 + 1) * 48 + lane] = keep1;
    }
}

// ===================== parallel scan: 3 passes =====================
// Pass 1: per-(b,seg,64-ch group) local scan from h=0 over SEGLEN tokens.
// Emits hseg[b][seg][s][d] (layout s-major for coalescing) and sumdt[b][seg][d].
__global__ __launch_bounds__(64) void scan_pass1(
    const float* __restrict__ xc, const float* __restrict__ dbl,
    const float* __restrict__ A_log, const float* __restrict__ dtW,
    const float* __restrict__ dtb,
    float* __restrict__ hseg, float* __restrict__ sumdt) {
    const int bid = blockIdx.x;
    const int dg = bid & 7;
    const int bs = bid >> 3;           // b*NSEG + seg
    const int d = (dg << 6) + threadIdx.x;
    const float LOG2E = 1.44269504088896340736f;
    float ArowL2[D_STATE], dWr[DT_RANK];
#pragma unroll
    for (int s4 = 0; s4 < 4; s4++) {
        float4 v = *(const float4*)(A_log + (size_t)d * D_STATE + s4 * 4);
        ArowL2[s4 * 4 + 0] = -__expf(v.x) * LOG2E;
        ArowL2[s4 * 4 + 1] = -__expf(v.y) * LOG2E;
        ArowL2[s4 * 4 + 2] = -__expf(v.z) * LOG2E;
        ArowL2[s4 * 4 + 3] = -__expf(v.w) * LOG2E;
        float4 w = *(const float4*)(dtW + (size_t)d * DT_RANK + s4 * 4);
        dWr[s4 * 4 + 0] = w.x; dWr[s4 * 4 + 1] = w.y;
        dWr[s4 * 4 + 2] = w.z; dWr[s4 * 4 + 3] = w.w;
    }
    const float dtbv = dtb[d];
    float h[D_STATE];
#pragma unroll
    for (int s = 0; s < D_STATE; s++) h[s] = 0.f;
    float sdt = 0.f;
    const int b = bs / NSEG, seg = bs % NSEG;
    const size_t tb = (size_t)b * SEQ + seg * SEGLEN;
    const float* __restrict__ dr = dbl + tb * 48;
    const float* __restrict__ xp = xc + tb * 512 + d;

    float cur[32], nxt[32];
#pragma unroll
    for (int i = 0; i < 8; i++) ((float4*)cur)[i] = ((const float4*)dr)[i];
    float xv = xp[0];
    for (int l = 0; l < SEGLEN; l++) {
        float nxv = 0.f;
        if (l + 1 < SEGLEN) {
            const float4* nr = (const float4*)(dr + (size_t)(l + 1) * 48);
#pragma unroll
            for (int i = 0; i < 8; i++) ((float4*)nxt)[i] = nr[i];
            nxv = xp[(size_t)(l + 1) * 512];
        }
        float a0 = dtbv, a1 = 0.f, a2 = 0.f, a3 = 0.f;
#pragma unroll
        for (int r = 0; r < 4; r++) {
            a0 = fmaf(cur[r], dWr[r], a0);
            a1 = fmaf(cur[4 + r], dWr[4 + r], a1);
            a2 = fmaf(cur[8 + r], dWr[8 + r], a2);
            a3 = fmaf(cur[12 + r], dWr[12 + r], a3);
        }
        float acc = (a0 + a1) + (a2 + a3);
        float dtt = fmaxf(acc, 0.f) + __logf(1.f + __expf(-fabsf(acc)));
        sdt += dtt;
        float dtx = dtt * xv;
#pragma unroll
        for (int s = 0; s < D_STATE; s++) {
            float dA = exp2f(dtt * ArowL2[s]);
            h[s] = fmaf(dA, h[s], dtx * cur[16 + s]);
        }
#pragma unroll
        for (int i = 0; i < 32; i++) cur[i] = nxt[i];
        xv = nxv;
    }
    float* hp = hseg + ((size_t)bs * 16) * 512 + d;
#pragma unroll
    for (int s = 0; s < D_STATE; s++) hp[(size_t)s * 512] = h[s];
    sumdt[(size_t)bs * 512 + d] = sdt;
}

// Pass 2: per-(b,d,s) sequential combine across segments.
// Hinit[b][seg][s][d] = state at segment start; H' = local + exp(A*sumdt)*H.
__global__ void scan_combine(const float* __restrict__ A_log,
                             const float* __restrict__ hseg,
                             const float* __restrict__ sumdt,
                             float* __restrict__ Hinit) {
    int tid = blockIdx.x * 256 + threadIdx.x;   // 0 .. 32*512*16-1
    int d = tid & 511;
    int s = (tid >> 9) & 15;
    int b = tid >> 13;
    float As = -__expf(A_log[d * D_STATE + s]);
    float H = 0.f;
    for (int seg = 0; seg < NSEG; seg++) {
        size_t bs = (size_t)b * NSEG + seg;
        size_t idx = (bs * 16 + s) * 512 + d;
        Hinit[idx] = H;
        float P = __expf(As * sumdt[bs * 512 + d]);
        H = fmaf(P, H, hseg[idx]);
    }
}

// Pass 3: re-run each segment from its corrected initial state; produce gated output.
// Writes output in-place over xc (same thread reads xc[t,d] then writes it).
__global__ __launch_bounds__(64) void scan_pass3(
    const float* __restrict__ dbl, const float* __restrict__ xz,
    const float* __restrict__ A_log, const float* __restrict__ Dskip,
    const float* __restrict__ dtW, const float* __restrict__ dtb,
    const float* __restrict__ Hinit, float* xc /* in+out, aliased */) {
    const int bid = blockIdx.x;
    const int dg = bid & 7;
    const int bs = bid >> 3;
    const int d = (dg << 6) + threadIdx.x;
    const float LOG2E = 1.44269504088896340736f;
    float ArowL2[D_STATE], dWr[DT_RANK];
#pragma unroll
    for (int s4 = 0; s4 < 4; s4++) {
        float4 v = *(const float4*)(A_log + (size_t)d * D_STATE + s4 * 4);
        ArowL2[s4 * 4 + 0] = -__expf(v.x) * LOG2E;
        ArowL2[s4 * 4 + 1] = -__expf(v.y) * LOG2E;
        ArowL2[s4 * 4 + 2] = -__expf(v.z) * LOG2E;
        ArowL2[s4 * 4 + 3] = -__expf(v.w) * LOG2E;
        float4 w = *(const float4*)(dtW + (size_t)d * DT_RANK + s4 * 4);
        dWr[s4 * 4 + 0] = w.x; dWr[s4 * 4 + 1] = w.y;
        dWr[s4 * 4 + 2] = w.z; dWr[s4 * 4 + 3] = w.w;
    }
    const float dtbv = dtb[d], dsk = Dskip[d];
    float h[D_STATE];
    {
        const float* hp = Hinit + ((size_t)bs * 16) * 512 + d;
#pragma unroll
        for (int s = 0; s < D_STATE; s++) h[s] = hp[(size_t)s * 512];
    }
    const int b = bs / NSEG, seg = bs % NSEG;
    const size_t tb = (size_t)b * SEQ + seg * SEGLEN;
    const float* __restrict__ dr = dbl + tb * 48;
    const float* xp = xc + tb * 512 + d;
    const float* __restrict__ zp = xz + tb * 1024 + 512 + d;
    float* yp = xc + tb * 512 + d;

    float cur[48], nxt[48];
#pragma unroll
    for (int i = 0; i < 12; i++) ((float4*)cur)[i] = ((const float4*)dr)[i];
    float xv = xp[0];
    float zv = zp[0];
    for (int l = 0; l < SEGLEN; l++) {
        float nxv = 0.f, nzv = 0.f;
        if (l + 1 < SEGLEN) {
            const float4* nr = (const float4*)(dr + (size_t)(l + 1) * 48);
#pragma unroll
            for (int i = 0; i < 12; i++) ((float4*)nxt)[i] = nr[i];
            nxv = xp[(size_t)(l + 1) * 512];
            nzv = zp[(size_t)(l + 1) * 1024];
        }
        float a0 = dtbv, a1 = 0.f, a2 = 0.f, a3 = 0.f;
#pragma unroll
        for (int r = 0; r < 4; r++) {
            a0 = fmaf(cur[r], dWr[r], a0);
            a1 = fmaf(cur[4 + r], dWr[4 + r], a1);
            a2 = fmaf(cur[8 + r], dWr[8 + r], a2);
            a3 = fmaf(cur[12 + r], dWr[12 + r], a3);
        }
        float acc = (a0 + a1) + (a2 + a3);
        float dtt = fmaxf(acc, 0.f) + __logf(1.f + __expf(-fabsf(acc)));
        float dtx = dtt * xv;
        float y0 = 0.f, y1 = 0.f, y2 = 0.f, y3 = 0.f;
#pragma unroll
        for (int s = 0; s < 4; s++) {
            float dA0 = exp2f(dtt * ArowL2[s]);
            float dA1 = exp2f(dtt * ArowL2[4 + s]);
            float dA2 = exp2f(dtt * ArowL2[8 + s]);
            float dA3 = exp2f(dtt * ArowL2[12 + s]);
            h[s] = fmaf(dA0, h[s], dtx * cur[16 + s]);
            h[4 + s] = fmaf(dA1, h[4 + s], dtx * cur[20 + s]);
            h[8 + s] = fmaf(dA2, h[8 + s], dtx * cur[24 + s]);
            h[12 + s] = fmaf(dA3, h[12 + s], dtx * cur[28 + s]);
            y0 = fmaf(h[s], cur[32 + s], y0);
            y1 = fmaf(h[4 + s], cur[36 + s], y1);
            y2 = fmaf(h[8 + s], cur[40 + s], y2);
            y3 = fmaf(h[12 + s], cur[44 + s], y3);
        }
        float y = (y0 + y1) + (y2 + y3);
        yp[(size_t)l * 512] = (y + xv * dsk) * (zv * fast_sig(zv));
#pragma unroll
        for (int i = 0; i < 48; i++) cur[i] = nxt[i];
        xv = nxv; zv = nzv;
    }
}

extern "C" void kernel_launch(void* const* d_in, const int* in_sizes, int n_in,
                              void* d_out, int out_size, void* d_ws, size_t ws_size,
                              hipStream_t stream) {
    const float* coords   = (const float*)d_in[0];
    const float* emb_W    = (const float*)d_in[1];
    const float* emb_b    = (const float*)d_in[2];
    const float* ln_w     = (const float*)d_in[3];
    const float* ln_b     = (const float*)d_in[4];
    const float* in_W     = (const float*)d_in[5];
    const float* conv_W   = (const float*)d_in[6];
    const float* conv_b   = (const float*)d_in[7];
    const float* xproj_W  = (const float*)d_in[8];
    const float* dtproj_W = (const float*)d_in[9];
    const float* dtproj_b = (const float*)d_in[10];
    const float* A_log    = (const float*)d_in[11];
    const float* D_skip   = (const float*)d_in[12];
    const float* out_W    = (const float*)d_in[13];
    const float* normf_w  = (const float*)d_in[14];
    const float* normf_b  = (const float*)d_in[15];
    const float* head_W   = (const float*)d_in[16];
    float* out = (float*)d_out;

    const int T = NTOK;  // 9600
    float* x     = (float*)d_ws;
    float* resid = x + (size_t)T * D_MODEL;
    float* h     = resid + (size_t)T * D_MODEL;
    float* xz    = h + (size_t)T * D_MODEL;
    float* xc    = xz + (size_t)T * 2 * D_INNER;   // also holds scan output (yv)
    float* dbl   = xc + (size_t)T * D_INNER;
    float* hseg  = dbl + (size_t)T * 48;                       // 32*10*16*512
    float* Hinit = hseg + (size_t)BATCH * NSEG * 16 * 512;     // 32*10*16*512
    float* sumdt = Hinit + (size_t)BATCH * NSEG * 16 * 512;    // 32*10*512

    embed_kernel<<<T, D_MODEL, 0, stream>>>(coords, emb_W, emb_b, x);

    for (int i = 0; i < N_LAYERS; i++) {
        ln_res_kernel<<<T, D_MODEL, 0, stream>>>(x, resid, h, ln_w + i * D_MODEL,
                                                 ln_b + i * D_MODEL, i == 0);
        gemm_tiled<128, 128, 8, 8, false><<<dim3(T / 128, 8), 256, 0, stream>>>(
            h, in_W + (size_t)i * 2 * D_INNER * D_MODEL, xz, 2 * D_INNER, D_MODEL);
        conv_xproj_kernel<<<T / 2, 64, 0, stream>>>(
            xz, conv_W + i * D_INNER * D_CONV, conv_b + i * D_INNER,
            xproj_W + (size_t)i * 48 * D_INNER, xc, dbl);
        const float* Ai = A_log + (size_t)i * D_INNER * D_STATE;
        const float* dWi = dtproj_W + (size_t)i * D_INNER * DT_RANK;
        const float* dbi = dtproj_b + i * D_INNER;
        scan_pass1<<<BATCH * NSEG * 8, 64, 0, stream>>>(xc, dbl, Ai, dWi, dbi, hseg, sumdt);
        scan_combine<<<(BATCH * D_INNER * D_STATE) / 256, 256, 0, stream>>>(
            Ai, hseg, sumdt, Hinit);
        scan_pass3<<<BATCH * NSEG * 8, 64, 0, stream>>>(
            dbl, xz, Ai, D_skip + i * D_INNER, dWi, dbi, Hinit, xc);
        gemm_tiled<128, 64, 8, 4, false><<<dim3(T / 128, 4), 256, 0, stream>>>(
            xc, out_W + (size_t)i * D_MODEL * D_INNER, x, D_MODEL, D_INNER);
    }

    final_rms_kernel<<<T, D_MODEL, 0, stream>>>(x, resid, normf_w, normf_b, h);
    gemm_tiled<128, 64, 8, 4, true><<<dim3(T / 128, 5), 256, 0, stream>>>(
        h, head_W, out, CITY, D_MODEL);
}

// Round 6
// 824.312 us; speedup vs baseline: 2.5852x; 1.5298x over previous
//
#include <hip/hip_runtime.h>
#include <hip/hip_bf16.h>
#include <math.h>

#define D_MODEL 256
#define D_INNER 512
#define D_STATE 16
#define D_CONV 4
#define DT_RANK 16
#define N_LAYERS 4
#define CITY 300
#define BATCH 32
#define SEQ 300
#define NTOK (BATCH * SEQ)   // 9600
#define NSEG 10
#define SEGLEN (SEQ / NSEG)  // 30

typedef __attribute__((ext_vector_type(8))) short short8v;
typedef __attribute__((ext_vector_type(4))) float f32x4;

__device__ __forceinline__ float fast_sig(float x) {
    return __builtin_amdgcn_rcpf(1.f + __expf(-x));
}

__device__ __forceinline__ unsigned int pack_bf16(float a, float b) {
    __hip_bfloat16 ha = __float2bfloat16(a);
    __hip_bfloat16 hb = __float2bfloat16(b);
    unsigned short ua = *reinterpret_cast<unsigned short*>(&ha);
    unsigned short ub = *reinterpret_cast<unsigned short*>(&hb);
    return (unsigned int)ua | ((unsigned int)ub << 16);
}

// ---------------- embedding ----------------
__global__ void embed_kernel(const float* __restrict__ coords,
                             const float* __restrict__ eW,
                             const float* __restrict__ eb,
                             float* __restrict__ x) {
    int t = blockIdx.x, d = threadIdx.x;
    float c0 = coords[t * 2 + 0];
    float c1 = coords[t * 2 + 1];
    x[t * D_MODEL + d] = c0 * eW[d * 2 + 0] + c1 * eW[d * 2 + 1] + eb[d];
}

// ------------- residual add + layernorm -------------
__global__ void ln_res_kernel(const float* __restrict__ xin, float* __restrict__ resid,
                              float* __restrict__ h,
                              const float* __restrict__ w,
                              const float* __restrict__ b, int first) {
    int t = blockIdx.x, d = threadIdx.x;
    float r = xin[t * D_MODEL + d] + (first ? 0.f : resid[t * D_MODEL + d]);
    resid[t * D_MODEL + d] = r;
    __shared__ float s1[D_MODEL], s2[D_MODEL];
    s1[d] = r; s2[d] = r * r;
    __syncthreads();
    for (int off = D_MODEL / 2; off > 0; off >>= 1) {
        if (d < off) { s1[d] += s1[d + off]; s2[d] += s2[d + off]; }
        __syncthreads();
    }
    float mean = s1[0] * (1.f / D_MODEL);
    float var = s2[0] * (1.f / D_MODEL) - mean * mean;
    h[t * D_MODEL + d] = (r - mean) * rsqrtf(var + 1e-5f) * w[d] + b[d];
}

// ------------- final add + RMSNorm -------------
__global__ void final_rms_kernel(const float* __restrict__ xin, const float* __restrict__ resid,
                                 const float* __restrict__ w,
                                 const float* __restrict__ b, float* __restrict__ h) {
    int t = blockIdx.x, d = threadIdx.x;
    float r = xin[t * D_MODEL + d] + resid[t * D_MODEL + d];
    __shared__ float s2[D_MODEL];
    s2[d] = r * r;
    __syncthreads();
    for (int off = D_MODEL / 2; off > 0; off >>= 1) {
        if (d < off) s2[d] += s2[d + off];
        __syncthreads();
    }
    float rms = r * rsqrtf(s2[0] * (1.f / D_MODEL) + 1e-5f);
    h[t * D_MODEL + d] = rms * w[d] + b[d];
}

// ------------- bf16 MFMA GEMM: C[t,n] = sum_k A[t,k] * W[n,k] -------------
// f32 in / f32 out; A,W converted to bf16 (RNE) while staging into LDS in
// MFMA-fragment order (lane's 8 bf16 contiguous -> conflict-free b128 reads).
// Block = 256 thr = 4 waves in 2x2; wave computes (BM/2)x(BN/2) via 16x16x32 MFMA.
template <int BM, int BN, bool GN>
__global__ __launch_bounds__(256, 2) void gemm_mfma(const float* __restrict__ A,
                                                    const float* __restrict__ W,
                                                    float* __restrict__ C, int N, int K) {
    constexpr int TI = BM / 32;  // 16-row tiles per wave (rows)
    constexpr int TJ = BN / 32;  // 16-col tiles per wave (cols)
    __shared__ short Als[BM * 32];
    __shared__ short Bls[BN * 32];
    const int tid = threadIdx.x;
    const int lane = tid & 63, wid = tid >> 6;
    const int wr = wid >> 1, wc = wid & 1;
    const int t0 = blockIdx.x * BM, n0 = blockIdx.y * BN;
    f32x4 acc[TI][TJ] = {};

    for (int k0 = 0; k0 < K; k0 += 32) {
        // stage A: rows m (0..BM), quads q; frag index ((m>>4)*4+q)*16 + (m&15)
#pragma unroll
        for (int it = 0; it < BM / 64; ++it) {
            int s = tid + it * 256;
            int m = s >> 2, q = s & 3;
            const float* src = A + (size_t)(t0 + m) * K + k0 + q * 8;
            float4 v0 = *(const float4*)src;
            float4 v1 = *(const float4*)(src + 4);
            uint4 p;
            p.x = pack_bf16(v0.x, v0.y);
            p.y = pack_bf16(v0.z, v0.w);
            p.z = pack_bf16(v1.x, v1.y);
            p.w = pack_bf16(v1.z, v1.w);
            *(uint4*)&Als[(((m >> 4) * 4 + q) * 16 + (m & 15)) * 8] = p;
        }
        // stage B (W rows are n-major x k: exactly the B^T layout MFMA wants)
#pragma unroll
        for (int it = 0; it < BN / 64; ++it) {
            int s = tid + it * 256;
            int n = s >> 2, q = s & 3;
            int nrow = n0 + n;
            float4 v0 = make_float4(0.f, 0.f, 0.f, 0.f), v1 = v0;
            if (!GN || nrow < N) {
                const float* src = W + (size_t)nrow * K + k0 + q * 8;
                v0 = *(const float4*)src;
                v1 = *(const float4*)(src + 4);
            }
            uint4 p;
            p.x = pack_bf16(v0.x, v0.y);
            p.y = pack_bf16(v0.z, v0.w);
            p.z = pack_bf16(v1.x, v1.y);
            p.w = pack_bf16(v1.z, v1.w);
            *(uint4*)&Bls[(((n >> 4) * 4 + q) * 16 + (n & 15)) * 8] = p;
        }
        __syncthreads();
        short8v af[TI], bf[TJ];
#pragma unroll
        for (int i = 0; i < TI; i++)
            af[i] = *(const short8v*)&Als[(wr * TI + i) * 512 + lane * 8];
#pragma unroll
        for (int j = 0; j < TJ; j++)
            bf[j] = *(const short8v*)&Bls[(wc * TJ + j) * 512 + lane * 8];
#pragma unroll
        for (int i = 0; i < TI; i++)
#pragma unroll
            for (int j = 0; j < TJ; j++)
                acc[i][j] = __builtin_amdgcn_mfma_f32_16x16x32_bf16(
                    af[i], bf[j], acc[i][j], 0, 0, 0);
        __syncthreads();
    }
    // epilogue: C/D layout col=lane&15, row=(lane>>4)*4+reg  [verified m89/m91]
    const int rq = lane >> 4, cn = lane & 15;
#pragma unroll
    for (int i = 0; i < TI; i++) {
        int trow = t0 + wr * (BM / 2) + i * 16 + rq * 4;
#pragma unroll
        for (int j = 0; j < TJ; j++) {
            int ncol = n0 + wc * (BN / 2) + j * 16 + cn;
            if (!GN || ncol < N) {
#pragma unroll
                for (int reg = 0; reg < 4; reg++)
                    C[(size_t)(trow + reg) * N + ncol] = acc[i][j][reg];
            }
        }
    }
}

// ------------- fused causal conv (k=4) + SiLU + xproj; wave = 2 tokens -------------
__global__ __launch_bounds__(64) void conv_xproj_kernel(
    const float* __restrict__ xz, const float* __restrict__ cW,
    const float* __restrict__ cb, const float* __restrict__ xW,
    float* __restrict__ xc, float* __restrict__ dbl) {
    const int lane = threadIdx.x;
    const int t0 = blockIdx.x * 2;
    const int ch = lane * 8;
    float4 cwv[8];
#pragma unroll
    for (int c = 0; c < 8; c++) cwv[c] = *(const float4*)(cW + (size_t)(ch + c) * 4);
    float4 cb0 = *(const float4*)(cb + ch);
    float4 cb1 = *(const float4*)(cb + ch + 4);
    float cbv[8] = {cb0.x, cb0.y, cb0.z, cb0.w, cb1.x, cb1.y, cb1.z, cb1.w};

    float x8[2][8];
#pragma unroll
    for (int tok = 0; tok < 2; tok++) {
        int t = t0 + tok;
        int l = t % SEQ;
        float accv[8];
#pragma unroll
        for (int c = 0; c < 8; c++) accv[c] = cbv[c];
#pragma unroll
        for (int k = 0; k < D_CONV; k++) {
            int ll = l - 3 + k;
            if (ll >= 0) {
                const float* src = xz + (size_t)(t - 3 + k) * 1024 + ch;
                float4 v0 = *(const float4*)src;
                float4 v1 = *(const float4*)(src + 4);
                float vv[8] = {v0.x, v0.y, v0.z, v0.w, v1.x, v1.y, v1.z, v1.w};
#pragma unroll
                for (int c = 0; c < 8; c++) {
                    float w = (k == 0) ? cwv[c].x : (k == 1) ? cwv[c].y
                             : (k == 2) ? cwv[c].z : cwv[c].w;
                    accv[c] = fmaf(vv[c], w, accv[c]);
                }
            }
        }
#pragma unroll
        for (int c = 0; c < 8; c++) {
            float a = accv[c];
            x8[tok][c] = a * fast_sig(a);
        }
        *(float4*)(xc + (size_t)t * 512 + ch) =
            make_float4(x8[tok][0], x8[tok][1], x8[tok][2], x8[tok][3]);
        *(float4*)(xc + (size_t)t * 512 + ch + 4) =
            make_float4(x8[tok][4], x8[tok][5], x8[tok][6], x8[tok][7]);
    }
    float keep0 = 0.f, keep1 = 0.f;
    for (int j = 0; j < 48; j++) {
        const float* wr = xW + (size_t)j * 512 + ch;
        float4 w0 = *(const float4*)wr;
        float4 w1 = *(const float4*)(wr + 4);
        float ww[8] = {w0.x, w0.y, w0.z, w0.w, w1.x, w1.y, w1.z, w1.w};
        float a0 = 0.f, a1 = 0.f;
#pragma unroll
        for (int c = 0; c < 8; c++) {
            a0 = fmaf(ww[c], x8[0][c], a0);
            a1 = fmaf(ww[c], x8[1][c], a1);
        }
#pragma unroll
        for (int m = 1; m < 64; m <<= 1) {
            a0 += __shfl_xor(a0, m);
            a1 += __shfl_xor(a1, m);
        }
        if (lane == j) { keep0 = a0; keep1 = a1; }
    }
    if (lane < 48) {
        dbl[(size_t)t0 * 48 + lane] = keep0;
        dbl[(size_t)(t0 + 1) * 48 + lane] = keep1;
    }
}

// ===================== parallel scan: 3 passes =====================
__global__ __launch_bounds__(64) void scan_pass1(
    const float* __restrict__ xc, const float* __restrict__ dbl,
    const float* __restrict__ A_log, const float* __restrict__ dtW,
    const float* __restrict__ dtb,
    float* __restrict__ hseg, float* __restrict__ sumdt) {
    const int bid = blockIdx.x;
    const int dg = bid & 7;
    const int bs = bid >> 3;           // b*NSEG + seg
    const int d = (dg << 6) + threadIdx.x;
    const float LOG2E = 1.44269504088896340736f;
    float ArowL2[D_STATE], dWr[DT_RANK];
#pragma unroll
    for (int s4 = 0; s4 < 4; s4++) {
        float4 v = *(const float4*)(A_log + (size_t)d * D_STATE + s4 * 4);
        ArowL2[s4 * 4 + 0] = -__expf(v.x) * LOG2E;
        ArowL2[s4 * 4 + 1] = -__expf(v.y) * LOG2E;
        ArowL2[s4 * 4 + 2] = -__expf(v.z) * LOG2E;
        ArowL2[s4 * 4 + 3] = -__expf(v.w) * LOG2E;
        float4 w = *(const float4*)(dtW + (size_t)d * DT_RANK + s4 * 4);
        dWr[s4 * 4 + 0] = w.x; dWr[s4 * 4 + 1] = w.y;
        dWr[s4 * 4 + 2] = w.z; dWr[s4 * 4 + 3] = w.w;
    }
    const float dtbv = dtb[d];
    float h[D_STATE];
#pragma unroll
    for (int s = 0; s < D_STATE; s++) h[s] = 0.f;
    float sdt = 0.f;
    const int b = bs / NSEG, seg = bs % NSEG;
    const size_t tb = (size_t)b * SEQ + seg * SEGLEN;
    const float* __restrict__ dr = dbl + tb * 48;
    const float* __restrict__ xp = xc + tb * 512 + d;

    float cur[32], nxt[32];
#pragma unroll
    for (int i = 0; i < 8; i++) ((float4*)cur)[i] = ((const float4*)dr)[i];
    float xv = xp[0];
    for (int l = 0; l < SEGLEN; l++) {
        float nxv = 0.f;
        if (l + 1 < SEGLEN) {
            const float4* nr = (const float4*)(dr + (size_t)(l + 1) * 48);
#pragma unroll
            for (int i = 0; i < 8; i++) ((float4*)nxt)[i] = nr[i];
            nxv = xp[(size_t)(l + 1) * 512];
        }
        float a0 = dtbv, a1 = 0.f, a2 = 0.f, a3 = 0.f;
#pragma unroll
        for (int r = 0; r < 4; r++) {
            a0 = fmaf(cur[r], dWr[r], a0);
            a1 = fmaf(cur[4 + r], dWr[4 + r], a1);
            a2 = fmaf(cur[8 + r], dWr[8 + r], a2);
            a3 = fmaf(cur[12 + r], dWr[12 + r], a3);
        }
        float acc = (a0 + a1) + (a2 + a3);
        float dtt = fmaxf(acc, 0.f) + __logf(1.f + __expf(-fabsf(acc)));
        sdt += dtt;
        float dtx = dtt * xv;
#pragma unroll
        for (int s = 0; s < D_STATE; s++) {
            float dA = exp2f(dtt * ArowL2[s]);
            h[s] = fmaf(dA, h[s], dtx * cur[16 + s]);
        }
#pragma unroll
        for (int i = 0; i < 32; i++) cur[i] = nxt[i];
        xv = nxv;
    }
    float* hp = hseg + ((size_t)bs * 16) * 512 + d;
#pragma unroll
    for (int s = 0; s < D_STATE; s++) hp[(size_t)s * 512] = h[s];
    sumdt[(size_t)bs * 512 + d] = sdt;
}

__global__ void scan_combine(const float* __restrict__ A_log,
                             const float* __restrict__ hseg,
                             const float* __restrict__ sumdt,
                             float* __restrict__ Hinit) {
    int tid = blockIdx.x * 256 + threadIdx.x;   // 0 .. 32*512*16-1
    int d = tid & 511;
    int s = (tid >> 9) & 15;
    int b = tid >> 13;
    float As = -__expf(A_log[d * D_STATE + s]);
    float H = 0.f;
    for (int seg = 0; seg < NSEG; seg++) {
        size_t bs = (size_t)b * NSEG + seg;
        size_t idx = (bs * 16 + s) * 512 + d;
        Hinit[idx] = H;
        float P = __expf(As * sumdt[bs * 512 + d]);
        H = fmaf(P, H, hseg[idx]);
    }
}

__global__ __launch_bounds__(64) void scan_pass3(
    const float* __restrict__ dbl, const float* __restrict__ xz,
    const float* __restrict__ A_log, const float* __restrict__ Dskip,
    const float* __restrict__ dtW, const float* __restrict__ dtb,
    const float* __restrict__ Hinit, float* xc /* in+out, aliased */) {
    const int bid = blockIdx.x;
    const int dg = bid & 7;
    const int bs = bid >> 3;
    const int d = (dg << 6) + threadIdx.x;
    const float LOG2E = 1.44269504088896340736f;
    float ArowL2[D_STATE], dWr[DT_RANK];
#pragma unroll
    for (int s4 = 0; s4 < 4; s4++) {
        float4 v = *(const float4*)(A_log + (size_t)d * D_STATE + s4 * 4);
        ArowL2[s4 * 4 + 0] = -__expf(v.x) * LOG2E;
        ArowL2[s4 * 4 + 1] = -__expf(v.y) * LOG2E;
        ArowL2[s4 * 4 + 2] = -__expf(v.z) * LOG2E;
        ArowL2[s4 * 4 + 3] = -__expf(v.w) * LOG2E;
        float4 w = *(const float4*)(dtW + (size_t)d * DT_RANK + s4 * 4);
        dWr[s4 * 4 + 0] = w.x; dWr[s4 * 4 + 1] = w.y;
        dWr[s4 * 4 + 2] = w.z; dWr[s4 * 4 + 3] = w.w;
    }
    const float dtbv = dtb[d], dsk = Dskip[d];
    float h[D_STATE];
    {
        const float* hp = Hinit + ((size_t)bs * 16) * 512 + d;
#pragma unroll
        for (int s = 0; s < D_STATE; s++) h[s] = hp[(size_t)s * 512];
    }
    const int b = bs / NSEG, seg = bs % NSEG;
    const size_t tb = (size_t)b * SEQ + seg * SEGLEN;
    const float* __restrict__ dr = dbl + tb * 48;
    const float* xp = xc + tb * 512 + d;
    const float* __restrict__ zp = xz + tb * 1024 + 512 + d;
    float* yp = xc + tb * 512 + d;

    float cur[48], nxt[48];
#pragma unroll
    for (int i = 0; i < 12; i++) ((float4*)cur)[i] = ((const float4*)dr)[i];
    float xv = xp[0];
    float zv = zp[0];
    for (int l = 0; l < SEGLEN; l++) {
        float nxv = 0.f, nzv = 0.f;
        if (l + 1 < SEGLEN) {
            const float4* nr = (const float4*)(dr + (size_t)(l + 1) * 48);
#pragma unroll
            for (int i = 0; i < 12; i++) ((float4*)nxt)[i] = nr[i];
            nxv = xp[(size_t)(l + 1) * 512];
            nzv = zp[(size_t)(l + 1) * 1024];
        }
        float a0 = dtbv, a1 = 0.f, a2 = 0.f, a3 = 0.f;
#pragma unroll
        for (int r = 0; r < 4; r++) {
            a0 = fmaf(cur[r], dWr[r], a0);
            a1 = fmaf(cur[4 + r], dWr[4 + r], a1);
            a2 = fmaf(cur[8 + r], dWr[8 + r], a2);
            a3 = fmaf(cur[12 + r], dWr[12 + r], a3);
        }
        float acc = (a0 + a1) + (a2 + a3);
        float dtt = fmaxf(acc, 0.f) + __logf(1.f + __expf(-fabsf(acc)));
        float dtx = dtt * xv;
        float y0 = 0.f, y1 = 0.f, y2 = 0.f, y3 = 0.f;
#pragma unroll
        for (int s = 0; s < 4; s++) {
            float dA0 = exp2f(dtt * ArowL2[s]);
            float dA1 = exp2f(dtt * ArowL2[4 + s]);
            float dA2 = exp2f(dtt * ArowL2[8 + s]);
            float dA3 = exp2f(dtt * ArowL2[12 + s]);
            h[s] = fmaf(dA0, h[s], dtx * cur[16 + s]);
            h[4 + s] = fmaf(dA1, h[4 + s], dtx * cur[20 + s]);
            h[8 + s] = fmaf(dA2, h[8 + s], dtx * cur[24 + s]);
            h[12 + s] = fmaf(dA3, h[12 + s], dtx * cur[28 + s]);
            y0 = fmaf(h[s], cur[32 + s], y0);
            y1 = fmaf(h[4 + s], cur[36 + s], y1);
            y2 = fmaf(h[8 + s], cur[40 + s], y2);
            y3 = fmaf(h[12 + s], cur[44 + s], y3);
        }
        float y = (y0 + y1) + (y2 + y3);
        yp[(size_t)l * 512] = (y + xv * dsk) * (zv * fast_sig(zv));
#pragma unroll
        for (int i = 0; i < 48; i++) cur[i] = nxt[i];
        xv = nxv; zv = nzv;
    }
}

extern "C" void kernel_launch(void* const* d_in, const int* in_sizes, int n_in,
                              void* d_out, int out_size, void* d_ws, size_t ws_size,
                              hipStream_t stream) {
    const float* coords   = (const float*)d_in[0];
    const float* emb_W    = (const float*)d_in[1];
    const float* emb_b    = (const float*)d_in[2];
    const float* ln_w     = (const float*)d_in[3];
    const float* ln_b     = (const float*)d_in[4];
    const float* in_W     = (const float*)d_in[5];
    const float* conv_W   = (const float*)d_in[6];
    const float* conv_b   = (const float*)d_in[7];
    const float* xproj_W  = (const float*)d_in[8];
    const float* dtproj_W = (const float*)d_in[9];
    const float* dtproj_b = (const float*)d_in[10];
    const float* A_log    = (const float*)d_in[11];
    const float* D_skip   = (const float*)d_in[12];
    const float* out_W    = (const float*)d_in[13];
    const float* normf_w  = (const float*)d_in[14];
    const float* normf_b  = (const float*)d_in[15];
    const float* head_W   = (const float*)d_in[16];
    float* out = (float*)d_out;

    const int T = NTOK;  // 9600
    float* x     = (float*)d_ws;
    float* resid = x + (size_t)T * D_MODEL;
    float* h     = resid + (size_t)T * D_MODEL;
    float* xz    = h + (size_t)T * D_MODEL;
    float* xc    = xz + (size_t)T * 2 * D_INNER;   // also holds scan output (yv)
    float* dbl   = xc + (size_t)T * D_INNER;
    float* hseg  = dbl + (size_t)T * 48;                       // 32*10*16*512
    float* Hinit = hseg + (size_t)BATCH * NSEG * 16 * 512;     // 32*10*16*512
    float* sumdt = Hinit + (size_t)BATCH * NSEG * 16 * 512;    // 32*10*512

    embed_kernel<<<T, D_MODEL, 0, stream>>>(coords, emb_W, emb_b, x);

    for (int i = 0; i < N_LAYERS; i++) {
        ln_res_kernel<<<T, D_MODEL, 0, stream>>>(x, resid, h, ln_w + i * D_MODEL,
                                                 ln_b + i * D_MODEL, i == 0);
        // in_proj: (9600,256) x (1024,256)^T -> (9600,1024)
        gemm_mfma<128, 128, false><<<dim3(T / 128, 8), 256, 0, stream>>>(
            h, in_W + (size_t)i * 2 * D_INNER * D_MODEL, xz, 2 * D_INNER, D_MODEL);
        conv_xproj_kernel<<<T / 2, 64, 0, stream>>>(
            xz, conv_W + i * D_INNER * D_CONV, conv_b + i * D_INNER,
            xproj_W + (size_t)i * 48 * D_INNER, xc, dbl);
        const float* Ai = A_log + (size_t)i * D_INNER * D_STATE;
        const float* dWi = dtproj_W + (size_t)i * D_INNER * DT_RANK;
        const float* dbi = dtproj_b + i * D_INNER;
        scan_pass1<<<BATCH * NSEG * 8, 64, 0, stream>>>(xc, dbl, Ai, dWi, dbi, hseg, sumdt);
        scan_combine<<<(BATCH * D_INNER * D_STATE) / 256, 256, 0, stream>>>(
            Ai, hseg, sumdt, Hinit);
        scan_pass3<<<BATCH * NSEG * 8, 64, 0, stream>>>(
            dbl, xz, Ai, D_skip + i * D_INNER, dWi, dbi, Hinit, xc);
        // out_proj: (9600,512) x (256,512)^T -> (9600,256)
        gemm_mfma<64, 64, false><<<dim3(T / 64, 4), 256, 0, stream>>>(
            xc, out_W + (size_t)i * D_MODEL * D_INNER, x, D_MODEL, D_INNER);
    }

    final_rms_kernel<<<T, D_MODEL, 0, stream>>>(x, resid, normf_w, normf_b, h);
    // head: (9600,256) x (300,256)^T -> (9600,300)
    gemm_mfma<64, 64, true><<<dim3(T / 64, 5), 256, 0, stream>>>(
        h, head_W, out, CITY, D_MODEL);
}

// Round 7
// 786.009 us; speedup vs baseline: 2.7112x; 1.0487x over previous
//
#include <hip/hip_runtime.h>
#include <hip/hip_bf16.h>
#include <math.h>

#define D_MODEL 256
#define D_INNER 512
#define D_STATE 16
#define D_CONV 4
#define DT_RANK 16
#define N_LAYERS 4
#define CITY 300
#define BATCH 32
#define SEQ 300
#define NTOK (BATCH * SEQ)   // 9600
#define NSEG 25
#define SEGLEN (SEQ / NSEG)  // 12

typedef __attribute__((ext_vector_type(8))) short short8v;
typedef __attribute__((ext_vector_type(4))) float f32x4;

__device__ __forceinline__ float fast_sig(float x) {
    return __builtin_amdgcn_rcpf(1.f + __expf(-x));
}

__device__ __forceinline__ unsigned int pack_bf16(float a, float b) {
    __hip_bfloat16 ha = __float2bfloat16(a);
    __hip_bfloat16 hb = __float2bfloat16(b);
    unsigned short ua = *reinterpret_cast<unsigned short*>(&ha);
    unsigned short ub = *reinterpret_cast<unsigned short*>(&hb);
    return (unsigned int)ua | ((unsigned int)ub << 16);
}

// ---------------- embedding ----------------
__global__ void embed_kernel(const float* __restrict__ coords,
                             const float* __restrict__ eW,
                             const float* __restrict__ eb,
                             float* __restrict__ x) {
    int t = blockIdx.x, d = threadIdx.x;
    float c0 = coords[t * 2 + 0];
    float c1 = coords[t * 2 + 1];
    x[t * D_MODEL + d] = c0 * eW[d * 2 + 0] + c1 * eW[d * 2 + 1] + eb[d];
}

// ------------- residual add + layernorm (wave shfl reduce, 2 barriers) -------------
__global__ void ln_res_kernel(const float* __restrict__ xin, float* __restrict__ resid,
                              float* __restrict__ h,
                              const float* __restrict__ w,
                              const float* __restrict__ b, int first) {
    int t = blockIdx.x, d = threadIdx.x;
    float r = xin[t * D_MODEL + d] + (first ? 0.f : resid[t * D_MODEL + d]);
    resid[t * D_MODEL + d] = r;
    float s1 = r, s2 = r * r;
#pragma unroll
    for (int m = 1; m < 64; m <<= 1) {
        s1 += __shfl_xor(s1, m);
        s2 += __shfl_xor(s2, m);
    }
    __shared__ float p1[4], p2[4];
    if ((d & 63) == 0) { p1[d >> 6] = s1; p2[d >> 6] = s2; }
    __syncthreads();
    s1 = (p1[0] + p1[1]) + (p1[2] + p1[3]);
    s2 = (p2[0] + p2[1]) + (p2[2] + p2[3]);
    float mean = s1 * (1.f / D_MODEL);
    float var = s2 * (1.f / D_MODEL) - mean * mean;
    h[t * D_MODEL + d] = (r - mean) * rsqrtf(var + 1e-5f) * w[d] + b[d];
}

// ------------- final add + RMSNorm -------------
__global__ void final_rms_kernel(const float* __restrict__ xin, const float* __restrict__ resid,
                                 const float* __restrict__ w,
                                 const float* __restrict__ b, float* __restrict__ h) {
    int t = blockIdx.x, d = threadIdx.x;
    float r = xin[t * D_MODEL + d] + resid[t * D_MODEL + d];
    float s2 = r * r;
#pragma unroll
    for (int m = 1; m < 64; m <<= 1) s2 += __shfl_xor(s2, m);
    __shared__ float p2[4];
    if ((d & 63) == 0) p2[d >> 6] = s2;
    __syncthreads();
    s2 = (p2[0] + p2[1]) + (p2[2] + p2[3]);
    float rms = r * rsqrtf(s2 * (1.f / D_MODEL) + 1e-5f);
    h[t * D_MODEL + d] = rms * w[d] + b[d];
}

// ------------- bf16 MFMA GEMM: C[t,n] = sum_k A[t,k] * W[n,k] -------------
template <int BM, int BN, bool GN>
__global__ __launch_bounds__(256, 2) void gemm_mfma(const float* __restrict__ A,
                                                    const float* __restrict__ W,
                                                    float* __restrict__ C, int N, int K) {
    constexpr int TI = BM / 32;
    constexpr int TJ = BN / 32;
    __shared__ short Als[BM * 32];
    __shared__ short Bls[BN * 32];
    const int tid = threadIdx.x;
    const int lane = tid & 63, wid = tid >> 6;
    const int wr = wid >> 1, wc = wid & 1;
    const int t0 = blockIdx.x * BM, n0 = blockIdx.y * BN;
    f32x4 acc[TI][TJ] = {};

    for (int k0 = 0; k0 < K; k0 += 32) {
#pragma unroll
        for (int it = 0; it < BM / 64; ++it) {
            int s = tid + it * 256;
            int m = s >> 2, q = s & 3;
            const float* src = A + (size_t)(t0 + m) * K + k0 + q * 8;
            float4 v0 = *(const float4*)src;
            float4 v1 = *(const float4*)(src + 4);
            uint4 p;
            p.x = pack_bf16(v0.x, v0.y);
            p.y = pack_bf16(v0.z, v0.w);
            p.z = pack_bf16(v1.x, v1.y);
            p.w = pack_bf16(v1.z, v1.w);
            *(uint4*)&Als[(((m >> 4) * 4 + q) * 16 + (m & 15)) * 8] = p;
        }
#pragma unroll
        for (int it = 0; it < BN / 64; ++it) {
            int s = tid + it * 256;
            int n = s >> 2, q = s & 3;
            int nrow = n0 + n;
            float4 v0 = make_float4(0.f, 0.f, 0.f, 0.f), v1 = v0;
            if (!GN || nrow < N) {
                const float* src = W + (size_t)nrow * K + k0 + q * 8;
                v0 = *(const float4*)src;
                v1 = *(const float4*)(src + 4);
            }
            uint4 p;
            p.x = pack_bf16(v0.x, v0.y);
            p.y = pack_bf16(v0.z, v0.w);
            p.z = pack_bf16(v1.x, v1.y);
            p.w = pack_bf16(v1.z, v1.w);
            *(uint4*)&Bls[(((n >> 4) * 4 + q) * 16 + (n & 15)) * 8] = p;
        }
        __syncthreads();
        short8v af[TI], bf[TJ];
#pragma unroll
        for (int i = 0; i < TI; i++)
            af[i] = *(const short8v*)&Als[(wr * TI + i) * 512 + lane * 8];
#pragma unroll
        for (int j = 0; j < TJ; j++)
            bf[j] = *(const short8v*)&Bls[(wc * TJ + j) * 512 + lane * 8];
#pragma unroll
        for (int i = 0; i < TI; i++)
#pragma unroll
            for (int j = 0; j < TJ; j++)
                acc[i][j] = __builtin_amdgcn_mfma_f32_16x16x32_bf16(
                    af[i], bf[j], acc[i][j], 0, 0, 0);
        __syncthreads();
    }
    const int rq = lane >> 4, cn = lane & 15;
#pragma unroll
    for (int i = 0; i < TI; i++) {
        int trow = t0 + wr * (BM / 2) + i * 16 + rq * 4;
#pragma unroll
        for (int j = 0; j < TJ; j++) {
            int ncol = n0 + wc * (BN / 2) + j * 16 + cn;
            if (!GN || ncol < N) {
#pragma unroll
                for (int reg = 0; reg < 4; reg++)
                    C[(size_t)(trow + reg) * N + ncol] = acc[i][j][reg];
            }
        }
    }
}

// ------------- causal depthwise conv (k=4) + bias + SiLU (elementwise) -------------
__global__ void conv_silu_kernel(const float* __restrict__ xz,
                                 const float* __restrict__ cW,
                                 const float* __restrict__ cb,
                                 float* __restrict__ xc) {
    int idx = blockIdx.x * blockDim.x + threadIdx.x;  // t*512 + d
    int d = idx & (D_INNER - 1);
    int t = idx >> 9;
    int l = t % SEQ;
    float acc = cb[d];
    float4 w = *(const float4*)(cW + d * 4);
#pragma unroll
    for (int k = 0; k < D_CONV; k++) {
        int ll = l - 3 + k;
        if (ll >= 0) {
            float wk = (k == 0) ? w.x : (k == 1) ? w.y : (k == 2) ? w.z : w.w;
            acc = fmaf(xz[(size_t)(t - 3 + k) * 1024 + d], wk, acc);
        }
    }
    xc[idx] = acc * fast_sig(acc);
}

// ===================== parallel scan: 3 passes, NSEG=25 =====================
// Pass 1: local scan from h=0 over SEGLEN tokens; emits hseg + sumdt.
__global__ __launch_bounds__(64) void scan_pass1(
    const float* __restrict__ xc, const float* __restrict__ dbl,
    const float* __restrict__ A_log, const float* __restrict__ dtW,
    const float* __restrict__ dtb,
    float* __restrict__ hseg, float* __restrict__ sumdt) {
    const int bid = blockIdx.x;
    const int dg = bid & 7;
    const int bs = bid >> 3;           // b*NSEG + seg
    const int d = (dg << 6) + threadIdx.x;
    const float LOG2E = 1.44269504088896340736f;
    float ArowL2[D_STATE], dWr[DT_RANK];
#pragma unroll
    for (int s4 = 0; s4 < 4; s4++) {
        float4 v = *(const float4*)(A_log + (size_t)d * D_STATE + s4 * 4);
        ArowL2[s4 * 4 + 0] = -__expf(v.x) * LOG2E;
        ArowL2[s4 * 4 + 1] = -__expf(v.y) * LOG2E;
        ArowL2[s4 * 4 + 2] = -__expf(v.z) * LOG2E;
        ArowL2[s4 * 4 + 3] = -__expf(v.w) * LOG2E;
        float4 w = *(const float4*)(dtW + (size_t)d * DT_RANK + s4 * 4);
        dWr[s4 * 4 + 0] = w.x; dWr[s4 * 4 + 1] = w.y;
        dWr[s4 * 4 + 2] = w.z; dWr[s4 * 4 + 3] = w.w;
    }
    const float dtbv = dtb[d];
    float h[D_STATE];
#pragma unroll
    for (int s = 0; s < D_STATE; s++) h[s] = 0.f;
    float sdt = 0.f;
    const int b = bs / NSEG, seg = bs % NSEG;
    const size_t tb = (size_t)b * SEQ + seg * SEGLEN;
    const float* __restrict__ dr = dbl + tb * 48;
    const float* __restrict__ xp = xc + tb * 512 + d;

    float db[2][32];
#pragma unroll
    for (int i = 0; i < 8; i++) ((float4*)db[0])[i] = ((const float4*)dr)[i];
    float xv = xp[0];
#pragma unroll
    for (int l = 0; l < SEGLEN; l++) {
        float* cur = db[l & 1];
        float* nxt = db[(l + 1) & 1];
        // unconditional prefetch of row l+1 (over-read lands in next ws array)
        const float4* nr = (const float4*)(dr + (size_t)(l + 1) * 48);
#pragma unroll
        for (int i = 0; i < 8; i++) ((float4*)nxt)[i] = nr[i];
        float nxv = xp[(size_t)(l + 1) * 512];
        float a0 = dtbv, a1 = 0.f, a2 = 0.f, a3 = 0.f;
#pragma unroll
        for (int r = 0; r < 4; r++) {
            a0 = fmaf(cur[r], dWr[r], a0);
            a1 = fmaf(cur[4 + r], dWr[4 + r], a1);
            a2 = fmaf(cur[8 + r], dWr[8 + r], a2);
            a3 = fmaf(cur[12 + r], dWr[12 + r], a3);
        }
        float acc = (a0 + a1) + (a2 + a3);
        float dtt = fmaxf(acc, 0.f) + __logf(1.f + __expf(-fabsf(acc)));
        sdt += dtt;
        float dtx = dtt * xv;
#pragma unroll
        for (int s = 0; s < D_STATE; s++) {
            float dA = exp2f(dtt * ArowL2[s]);
            h[s] = fmaf(dA, h[s], dtx * cur[16 + s]);
        }
        xv = nxv;
    }
    float* hp = hseg + ((size_t)bs * 16) * 512 + d;
#pragma unroll
    for (int s = 0; s < D_STATE; s++) hp[(size_t)s * 512] = h[s];
    sumdt[(size_t)bs * 512 + d] = sdt;
}

// Pass 2: in-place combine; hseg[idx] becomes the segment's INITIAL state.
__global__ void scan_combine(const float* __restrict__ A_log,
                             float* __restrict__ hseg,
                             const float* __restrict__ sumdt) {
    int tid = blockIdx.x * 256 + threadIdx.x;   // 0 .. 32*512*16-1
    int d = tid & 511;
    int s = (tid >> 9) & 15;
    int b = tid >> 13;
    float As = -__expf(A_log[d * D_STATE + s]);
    float H = 0.f;
    for (int seg = 0; seg < NSEG; seg++) {
        size_t bs = (size_t)b * NSEG + seg;
        size_t idx = (bs * 16 + s) * 512 + d;
        float hl = hseg[idx];
        hseg[idx] = H;                 // initial state for this segment
        float P = __expf(As * sumdt[bs * 512 + d]);
        H = fmaf(P, H, hl);
    }
}

// Pass 3: re-run each segment from its initial state; gated output over xc.
__global__ __launch_bounds__(64) void scan_pass3(
    const float* __restrict__ dbl, const float* __restrict__ xz,
    const float* __restrict__ A_log, const float* __restrict__ Dskip,
    const float* __restrict__ dtW, const float* __restrict__ dtb,
    const float* __restrict__ Hinit, float* xc /* in+out, aliased */) {
    const int bid = blockIdx.x;
    const int dg = bid & 7;
    const int bs = bid >> 3;
    const int d = (dg << 6) + threadIdx.x;
    const float LOG2E = 1.44269504088896340736f;
    float ArowL2[D_STATE], dWr[DT_RANK];
#pragma unroll
    for (int s4 = 0; s4 < 4; s4++) {
        float4 v = *(const float4*)(A_log + (size_t)d * D_STATE + s4 * 4);
        ArowL2[s4 * 4 + 0] = -__expf(v.x) * LOG2E;
        ArowL2[s4 * 4 + 1] = -__expf(v.y) * LOG2E;
        ArowL2[s4 * 4 + 2] = -__expf(v.z) * LOG2E;
        ArowL2[s4 * 4 + 3] = -__expf(v.w) * LOG2E;
        float4 w = *(const float4*)(dtW + (size_t)d * DT_RANK + s4 * 4);
        dWr[s4 * 4 + 0] = w.x; dWr[s4 * 4 + 1] = w.y;
        dWr[s4 * 4 + 2] = w.z; dWr[s4 * 4 + 3] = w.w;
    }
    const float dtbv = dtb[d], dsk = Dskip[d];
    float h[D_STATE];
    {
        const float* hp = Hinit + ((size_t)bs * 16) * 512 + d;
#pragma unroll
        for (int s = 0; s < D_STATE; s++) h[s] = hp[(size_t)s * 512];
    }
    const int b = bs / NSEG, seg = bs % NSEG;
    const size_t tb = (size_t)b * SEQ + seg * SEGLEN;
    const float* __restrict__ dr = dbl + tb * 48;
    const float* xp = xc + tb * 512 + d;
    const float* __restrict__ zp = xz + tb * 1024 + 512 + d;
    float* yp = xc + tb * 512 + d;

    float db[2][48];
#pragma unroll
    for (int i = 0; i < 12; i++) ((float4*)db[0])[i] = ((const float4*)dr)[i];
    float xv = xp[0];
    float zv = zp[0];
#pragma unroll
    for (int l = 0; l < SEGLEN; l++) {
        float* cur = db[l & 1];
        float* nxt = db[(l + 1) & 1];
        const float4* nr = (const float4*)(dr + (size_t)(l + 1) * 48);
#pragma unroll
        for (int i = 0; i < 12; i++) ((float4*)nxt)[i] = nr[i];
        float nxv = xp[(size_t)(l + 1) * 512];
        float nzv = zp[(size_t)(l + 1) * 1024];
        float a0 = dtbv, a1 = 0.f, a2 = 0.f, a3 = 0.f;
#pragma unroll
        for (int r = 0; r < 4; r++) {
            a0 = fmaf(cur[r], dWr[r], a0);
            a1 = fmaf(cur[4 + r], dWr[4 + r], a1);
            a2 = fmaf(cur[8 + r], dWr[8 + r], a2);
            a3 = fmaf(cur[12 + r], dWr[12 + r], a3);
        }
        float acc = (a0 + a1) + (a2 + a3);
        float dtt = fmaxf(acc, 0.f) + __logf(1.f + __expf(-fabsf(acc)));
        float dtx = dtt * xv;
        float y0 = 0.f, y1 = 0.f, y2 = 0.f, y3 = 0.f;
#pragma unroll
        for (int s = 0; s < 4; s++) {
            float dA0 = exp2f(dtt * ArowL2[s]);
            float dA1 = exp2f(dtt * ArowL2[4 + s]);
            float dA2 = exp2f(dtt * ArowL2[8 + s]);
            float dA3 = exp2f(dtt * ArowL2[12 + s]);
            h[s] = fmaf(dA0, h[s], dtx * cur[16 + s]);
            h[4 + s] = fmaf(dA1, h[4 + s], dtx * cur[20 + s]);
            h[8 + s] = fmaf(dA2, h[8 + s], dtx * cur[24 + s]);
            h[12 + s] = fmaf(dA3, h[12 + s], dtx * cur[28 + s]);
            y0 = fmaf(h[s], cur[32 + s], y0);
            y1 = fmaf(h[4 + s], cur[36 + s], y1);
            y2 = fmaf(h[8 + s], cur[40 + s], y2);
            y3 = fmaf(h[12 + s], cur[44 + s], y3);
        }
        float y = (y0 + y1) + (y2 + y3);
        yp[(size_t)l * 512] = (y + xv * dsk) * (zv * fast_sig(zv));
        xv = nxv; zv = nzv;
    }
}

extern "C" void kernel_launch(void* const* d_in, const int* in_sizes, int n_in,
                              void* d_out, int out_size, void* d_ws, size_t ws_size,
                              hipStream_t stream) {
    const float* coords   = (const float*)d_in[0];
    const float* emb_W    = (const float*)d_in[1];
    const float* emb_b    = (const float*)d_in[2];
    const float* ln_w     = (const float*)d_in[3];
    const float* ln_b     = (const float*)d_in[4];
    const float* in_W     = (const float*)d_in[5];
    const float* conv_W   = (const float*)d_in[6];
    const float* conv_b   = (const float*)d_in[7];
    const float* xproj_W  = (const float*)d_in[8];
    const float* dtproj_W = (const float*)d_in[9];
    const float* dtproj_b = (const float*)d_in[10];
    const float* A_log    = (const float*)d_in[11];
    const float* D_skip   = (const float*)d_in[12];
    const float* out_W    = (const float*)d_in[13];
    const float* normf_w  = (const float*)d_in[14];
    const float* normf_b  = (const float*)d_in[15];
    const float* head_W   = (const float*)d_in[16];
    float* out = (float*)d_out;

    const int T = NTOK;  // 9600
    float* x     = (float*)d_ws;
    float* resid = x + (size_t)T * D_MODEL;
    float* h     = resid + (size_t)T * D_MODEL;
    float* xz    = h + (size_t)T * D_MODEL;
    float* xc    = xz + (size_t)T * 2 * D_INNER;   // also holds scan output
    float* dbl   = xc + (size_t)T * D_INNER;
    float* hseg  = dbl + (size_t)T * 48;                       // 32*25*16*512 (in-place Hinit)
    float* sumdt = hseg + (size_t)BATCH * NSEG * 16 * 512;     // 32*25*512

    embed_kernel<<<T, D_MODEL, 0, stream>>>(coords, emb_W, emb_b, x);

    for (int i = 0; i < N_LAYERS; i++) {
        ln_res_kernel<<<T, D_MODEL, 0, stream>>>(x, resid, h, ln_w + i * D_MODEL,
                                                 ln_b + i * D_MODEL, i == 0);
        // in_proj: (9600,256) x (1024,256)^T -> (9600,1024)
        gemm_mfma<128, 128, false><<<dim3(T / 128, 8), 256, 0, stream>>>(
            h, in_W + (size_t)i * 2 * D_INNER * D_MODEL, xz, 2 * D_INNER, D_MODEL);
        conv_silu_kernel<<<T * D_INNER / 256, 256, 0, stream>>>(
            xz, conv_W + i * D_INNER * D_CONV, conv_b + i * D_INNER, xc);
        // xproj: (9600,512) x (48,512)^T -> (9600,48)
        gemm_mfma<64, 64, true><<<dim3(T / 64, 1), 256, 0, stream>>>(
            xc, xproj_W + (size_t)i * 48 * D_INNER, dbl, 48, D_INNER);
        const float* Ai = A_log + (size_t)i * D_INNER * D_STATE;
        const float* dWi = dtproj_W + (size_t)i * D_INNER * DT_RANK;
        const float* dbi = dtproj_b + i * D_INNER;
        scan_pass1<<<BATCH * NSEG * 8, 64, 0, stream>>>(xc, dbl, Ai, dWi, dbi, hseg, sumdt);
        scan_combine<<<(BATCH * D_INNER * D_STATE) / 256, 256, 0, stream>>>(
            Ai, hseg, sumdt);
        scan_pass3<<<BATCH * NSEG * 8, 64, 0, stream>>>(
            dbl, xz, Ai, D_skip + i * D_INNER, dWi, dbi, hseg, xc);
        // out_proj: (9600,512) x (256,512)^T -> (9600,256)
        gemm_mfma<64, 64, false><<<dim3(T / 64, 4), 256, 0, stream>>>(
            xc, out_W + (size_t)i * D_MODEL * D_INNER, x, D_MODEL, D_INNER);
    }

    final_rms_kernel<<<T, D_MODEL, 0, stream>>>(x, resid, normf_w, normf_b, h);
    // head: (9600,256) x (300,256)^T -> (9600,300)
    gemm_mfma<64, 64, true><<<dim3(T / 64, 5), 256, 0, stream>>>(
        h, head_W, out, CITY, D_MODEL);
}

// Round 9
// 755.286 us; speedup vs baseline: 2.8214x; 1.0407x over previous
//
#include <hip/hip_runtime.h>
#include <hip/hip_bf16.h>
#include <math.h>

#define D_MODEL 256
#define D_INNER 512
#define D_STATE 16
#define D_CONV 4
#define DT_RANK 16
#define N_LAYERS 4
#define CITY 300
#define BATCH 32
#define SEQ 300
#define NTOK (BATCH * SEQ)   // 9600
#define NSEG 12
#define SEGLEN (SEQ / NSEG)  // 25

typedef __attribute__((ext_vector_type(8))) short short8v;
typedef __attribute__((ext_vector_type(4))) float f32x4;

__device__ __forceinline__ float fast_sig(float x) {
    return __builtin_amdgcn_rcpf(1.f + __expf(-x));
}

__device__ __forceinline__ unsigned int pack_bf16(float a, float b) {
    __hip_bfloat16 ha = __float2bfloat16(a);
    __hip_bfloat16 hb = __float2bfloat16(b);
    unsigned short ua = *reinterpret_cast<unsigned short*>(&ha);
    unsigned short ub = *reinterpret_cast<unsigned short*>(&hb);
    return (unsigned int)ua | ((unsigned int)ub << 16);
}

// ---------------- embedding ----------------
__global__ void embed_kernel(const float* __restrict__ coords,
                             const float* __restrict__ eW,
                             const float* __restrict__ eb,
                             float* __restrict__ x) {
    int t = blockIdx.x, d = threadIdx.x;
    float c0 = coords[t * 2 + 0];
    float c1 = coords[t * 2 + 1];
    x[t * D_MODEL + d] = c0 * eW[d * 2 + 0] + c1 * eW[d * 2 + 1] + eb[d];
}

// ------------- residual add + layernorm -------------
__global__ void ln_res_kernel(const float* __restrict__ xin, float* __restrict__ resid,
                              float* __restrict__ h,
                              const float* __restrict__ w,
                              const float* __restrict__ b, int first) {
    int t = blockIdx.x, d = threadIdx.x;
    float r = xin[t * D_MODEL + d] + (first ? 0.f : resid[t * D_MODEL + d]);
    resid[t * D_MODEL + d] = r;
    float s1 = r, s2 = r * r;
#pragma unroll
    for (int m = 1; m < 64; m <<= 1) {
        s1 += __shfl_xor(s1, m);
        s2 += __shfl_xor(s2, m);
    }
    __shared__ float p1[4], p2[4];
    if ((d & 63) == 0) { p1[d >> 6] = s1; p2[d >> 6] = s2; }
    __syncthreads();
    s1 = (p1[0] + p1[1]) + (p1[2] + p1[3]);
    s2 = (p2[0] + p2[1]) + (p2[2] + p2[3]);
    float mean = s1 * (1.f / D_MODEL);
    float var = s2 * (1.f / D_MODEL) - mean * mean;
    h[t * D_MODEL + d] = (r - mean) * rsqrtf(var + 1e-5f) * w[d] + b[d];
}

// ------------- final add + RMSNorm -------------
__global__ void final_rms_kernel(const float* __restrict__ xin, const float* __restrict__ resid,
                                 const float* __restrict__ w,
                                 const float* __restrict__ b, float* __restrict__ h) {
    int t = blockIdx.x, d = threadIdx.x;
    float r = xin[t * D_MODEL + d] + resid[t * D_MODEL + d];
    float s2 = r * r;
#pragma unroll
    for (int m = 1; m < 64; m <<= 1) s2 += __shfl_xor(s2, m);
    __shared__ float p2[4];
    if ((d & 63) == 0) p2[d >> 6] = s2;
    __syncthreads();
    s2 = (p2[0] + p2[1]) + (p2[2] + p2[3]);
    float rms = r * rsqrtf(s2 * (1.f / D_MODEL) + 1e-5f);
    h[t * D_MODEL + d] = rms * w[d] + b[d];
}

// ------------- bf16 MFMA GEMM: C[t,n] = sum_k A[t,k] * W[n,k] -------------
template <int BM, int BN, bool GN>
__global__ __launch_bounds__(256, 2) void gemm_mfma(const float* __restrict__ A,
                                                    const float* __restrict__ W,
                                                    float* __restrict__ C, int N, int K) {
    constexpr int TI = BM / 32;
    constexpr int TJ = BN / 32;
    __shared__ short Als[BM * 32];
    __shared__ short Bls[BN * 32];
    const int tid = threadIdx.x;
    const int lane = tid & 63, wid = tid >> 6;
    const int wr = wid >> 1, wc = wid & 1;
    const int t0 = blockIdx.x * BM, n0 = blockIdx.y * BN;
    f32x4 acc[TI][TJ] = {};

    for (int k0 = 0; k0 < K; k0 += 32) {
#pragma unroll
        for (int it = 0; it < BM / 64; ++it) {
            int s = tid + it * 256;
            int m = s >> 2, q = s & 3;
            const float* src = A + (size_t)(t0 + m) * K + k0 + q * 8;
            float4 v0 = *(const float4*)src;
            float4 v1 = *(const float4*)(src + 4);
            uint4 p;
            p.x = pack_bf16(v0.x, v0.y);
            p.y = pack_bf16(v0.z, v0.w);
            p.z = pack_bf16(v1.x, v1.y);
            p.w = pack_bf16(v1.z, v1.w);
            *(uint4*)&Als[(((m >> 4) * 4 + q) * 16 + (m & 15)) * 8] = p;
        }
#pragma unroll
        for (int it = 0; it < BN / 64; ++it) {
            int s = tid + it * 256;
            int n = s >> 2, q = s & 3;
            int nrow = n0 + n;
            float4 v0 = make_float4(0.f, 0.f, 0.f, 0.f), v1 = v0;
            if (!GN || nrow < N) {
                const float* src = W + (size_t)nrow * K + k0 + q * 8;
                v0 = *(const float4*)src;
                v1 = *(const float4*)(src + 4);
            }
            uint4 p;
            p.x = pack_bf16(v0.x, v0.y);
            p.y = pack_bf16(v0.z, v0.w);
            p.z = pack_bf16(v1.x, v1.y);
            p.w = pack_bf16(v1.z, v1.w);
            *(uint4*)&Bls[(((n >> 4) * 4 + q) * 16 + (n & 15)) * 8] = p;
        }
        __syncthreads();
        short8v af[TI], bf[TJ];
#pragma unroll
        for (int i = 0; i < TI; i++)
            af[i] = *(const short8v*)&Als[(wr * TI + i) * 512 + lane * 8];
#pragma unroll
        for (int j = 0; j < TJ; j++)
            bf[j] = *(const short8v*)&Bls[(wc * TJ + j) * 512 + lane * 8];
#pragma unroll
        for (int i = 0; i < TI; i++)
#pragma unroll
            for (int j = 0; j < TJ; j++)
                acc[i][j] = __builtin_amdgcn_mfma_f32_16x16x32_bf16(
                    af[i], bf[j], acc[i][j], 0, 0, 0);
        __syncthreads();
    }
    const int rq = lane >> 4, cn = lane & 15;
#pragma unroll
    for (int i = 0; i < TI; i++) {
        int trow = t0 + wr * (BM / 2) + i * 16 + rq * 4;
#pragma unroll
        for (int j = 0; j < TJ; j++) {
            int ncol = n0 + wc * (BN / 2) + j * 16 + cn;
            if (!GN || ncol < N) {
#pragma unroll
                for (int reg = 0; reg < 4; reg++)
                    C[(size_t)(trow + reg) * N + ncol] = acc[i][j][reg];
            }
        }
    }
}

// ------------- causal depthwise conv (k=4) + bias + SiLU, float4 -------------
__global__ void conv_silu_kernel(const float* __restrict__ xz,
                                 const float* __restrict__ cW,
                                 const float* __restrict__ cb,
                                 float* __restrict__ xc) {
    int idx = blockIdx.x * blockDim.x + threadIdx.x;  // 4-channel groups
    int d4 = (idx & 127) * 4;
    int t = idx >> 7;
    int l = t % SEQ;
    float4 acc = *(const float4*)(cb + d4);
    float4 wA = *(const float4*)(cW + (d4 + 0) * 4);
    float4 wB = *(const float4*)(cW + (d4 + 1) * 4);
    float4 wC = *(const float4*)(cW + (d4 + 2) * 4);
    float4 wD = *(const float4*)(cW + (d4 + 3) * 4);
#pragma unroll
    for (int k = 0; k < D_CONV; k++) {
        int ll = l - 3 + k;
        if (ll >= 0) {
            float4 v = *(const float4*)(xz + (size_t)(t - 3 + k) * 1024 + d4);
            float wa = (k == 0) ? wA.x : (k == 1) ? wA.y : (k == 2) ? wA.z : wA.w;
            float wb = (k == 0) ? wB.x : (k == 1) ? wB.y : (k == 2) ? wB.z : wB.w;
            float wc = (k == 0) ? wC.x : (k == 1) ? wC.y : (k == 2) ? wC.z : wC.w;
            float wd = (k == 0) ? wD.x : (k == 1) ? wD.y : (k == 2) ? wD.z : wD.w;
            acc.x = fmaf(v.x, wa, acc.x);
            acc.y = fmaf(v.y, wb, acc.y);
            acc.z = fmaf(v.z, wc, acc.z);
            acc.w = fmaf(v.w, wd, acc.w);
        }
    }
    float4 o;
    o.x = acc.x * fast_sig(acc.x);
    o.y = acc.y * fast_sig(acc.y);
    o.z = acc.z * fast_sig(acc.z);
    o.w = acc.w * fast_sig(acc.w);
    *(float4*)(xc + (size_t)t * 512 + d4) = o;
}

// ========== single-block-per-(b,dg) 3-phase scan; combine in LDS ==========
// grid (8,32) = (dg, b); block 768 thr = 12 waves; wave w = segment w.
// Phase1: wave scans its segment from h=0, writes h_end+sumdt to LDS.
// Phase2: 768 threads combine 1024 (s,ch) items over 12 segments in LDS
//         (hseg entry becomes segment's INITIAL state).
// Phase3: wave re-scans from its initial state, writes gated output over xc.
__global__ __launch_bounds__(768) void scan_block(
    float* xcio, const float* __restrict__ dbl, const float* __restrict__ xz,
    const float* __restrict__ A_log, const float* __restrict__ Dskip,
    const float* __restrict__ dtW, const float* __restrict__ dtb,
    float* __restrict__ yout) {
    __shared__ float lh[NSEG * D_STATE * 64];   // [seg][s][ch]
    __shared__ float lsd[NSEG * 64];            // [seg][ch]
    const int dg = blockIdx.x, b = blockIdx.y;
    const int tid = threadIdx.x;
    const int lane = tid & 63, seg = tid >> 6;
    const int d = (dg << 6) + lane;
    const float LOG2E = 1.44269504088896340736f;
    float ArowL2[D_STATE], dWr[DT_RANK];
#pragma unroll
    for (int s4 = 0; s4 < 4; s4++) {
        float4 v = *(const float4*)(A_log + (size_t)d * D_STATE + s4 * 4);
        ArowL2[s4 * 4 + 0] = -__expf(v.x) * LOG2E;
        ArowL2[s4 * 4 + 1] = -__expf(v.y) * LOG2E;
        ArowL2[s4 * 4 + 2] = -__expf(v.z) * LOG2E;
        ArowL2[s4 * 4 + 3] = -__expf(v.w) * LOG2E;
        float4 w = *(const float4*)(dtW + (size_t)d * DT_RANK + s4 * 4);
        dWr[s4 * 4 + 0] = w.x; dWr[s4 * 4 + 1] = w.y;
        dWr[s4 * 4 + 2] = w.z; dWr[s4 * 4 + 3] = w.w;
    }
    const float dtbv = dtb[d], dsk = Dskip[d];
    const size_t tb = (size_t)b * SEQ + seg * SEGLEN;
    const float* __restrict__ dr = dbl + tb * 48;
    const float* xp = xcio + tb * 512 + d;
    const float* __restrict__ zp = xz + tb * 1024 + 512 + d;
    float* yp = yout + tb * 512 + d;

    // ---------------- phase 1: local scan from h=0 ----------------
    {
        float h[D_STATE];
#pragma unroll
        for (int s = 0; s < D_STATE; s++) h[s] = 0.f;
        float sdt = 0.f;
        float dbA[32], dbB[32];
#pragma unroll
        for (int i = 0; i < 8; i++) ((float4*)dbA)[i] = ((const float4*)dr)[i];
        float xv = xp[0];
        for (int l = 0; l < SEGLEN; l += 2) {
            const float4* nr1 = (const float4*)(dr + (size_t)(l + 1) * 48);
#pragma unroll
            for (int i = 0; i < 8; i++) ((float4*)dbB)[i] = nr1[i];
            float xv1 = xp[(size_t)(l + 1) * 512];
            {
                float a0 = dtbv, a1 = 0.f, a2 = 0.f, a3 = 0.f;
#pragma unroll
                for (int r = 0; r < 4; r++) {
                    a0 = fmaf(dbA[r], dWr[r], a0);
                    a1 = fmaf(dbA[4 + r], dWr[4 + r], a1);
                    a2 = fmaf(dbA[8 + r], dWr[8 + r], a2);
                    a3 = fmaf(dbA[12 + r], dWr[12 + r], a3);
                }
                float acc = (a0 + a1) + (a2 + a3);
                float dtt = fmaxf(acc, 0.f) + __logf(1.f + __expf(-fabsf(acc)));
                sdt += dtt;
                float dtx = dtt * xv;
#pragma unroll
                for (int s = 0; s < D_STATE; s++) {
                    float dA = exp2f(dtt * ArowL2[s]);
                    h[s] = fmaf(dA, h[s], dtx * dbA[16 + s]);
                }
            }
            const float4* nr2 = (const float4*)(dr + (size_t)(l + 2) * 48);
#pragma unroll
            for (int i = 0; i < 8; i++) ((float4*)dbA)[i] = nr2[i];
            float xv2 = xp[(size_t)(l + 2) * 512];
            if (l + 1 < SEGLEN) {
                float a0 = dtbv, a1 = 0.f, a2 = 0.f, a3 = 0.f;
#pragma unroll
                for (int r = 0; r < 4; r++) {
                    a0 = fmaf(dbB[r], dWr[r], a0);
                    a1 = fmaf(dbB[4 + r], dWr[4 + r], a1);
                    a2 = fmaf(dbB[8 + r], dWr[8 + r], a2);
                    a3 = fmaf(dbB[12 + r], dWr[12 + r], a3);
                }
                float acc = (a0 + a1) + (a2 + a3);
                float dtt = fmaxf(acc, 0.f) + __logf(1.f + __expf(-fabsf(acc)));
                sdt += dtt;
                float dtx = dtt * xv1;
#pragma unroll
                for (int s = 0; s < D_STATE; s++) {
                    float dA = exp2f(dtt * ArowL2[s]);
                    h[s] = fmaf(dA, h[s], dtx * dbB[16 + s]);
                }
            }
            xv = xv2;
        }
#pragma unroll
        for (int s = 0; s < D_STATE; s++) lh[(seg * D_STATE + s) * 64 + lane] = h[s];
        lsd[seg * 64 + lane] = sdt;
    }
    __syncthreads();
    // ---------------- phase 2: in-LDS prefix combine ----------------
    for (int it = tid; it < D_STATE * 64; it += 768) {
        int ch = it & 63, s = it >> 6;
        float As2 = -__expf(A_log[(size_t)((dg << 6) + ch) * D_STATE + s]) * LOG2E;
        float H = 0.f;
        for (int sg = 0; sg < NSEG; sg++) {
            float hl = lh[(sg * D_STATE + s) * 64 + ch];
            float sd = lsd[sg * 64 + ch];
            lh[(sg * D_STATE + s) * 64 + ch] = H;
            H = fmaf(exp2f(As2 * sd), H, hl);
        }
    }
    __syncthreads();
    // ---------------- phase 3: re-scan from initial state ----------------
    {
        float h[D_STATE];
#pragma unroll
        for (int s = 0; s < D_STATE; s++) h[s] = lh[(seg * D_STATE + s) * 64 + lane];
        float dbA[48], dbB[48];
#pragma unroll
        for (int i = 0; i < 12; i++) ((float4*)dbA)[i] = ((const float4*)dr)[i];
        float xv = xp[0], zv = zp[0];
        for (int l = 0; l < SEGLEN; l += 2) {
            const float4* nr1 = (const float4*)(dr + (size_t)(l + 1) * 48);
#pragma unroll
            for (int i = 0; i < 12; i++) ((float4*)dbB)[i] = nr1[i];
            float xv1 = xp[(size_t)(l + 1) * 512];
            float zv1 = zp[(size_t)(l + 1) * 1024];
            {
                float a0 = dtbv, a1 = 0.f, a2 = 0.f, a3 = 0.f;
#pragma unroll
                for (int r = 0; r < 4; r++) {
                    a0 = fmaf(dbA[r], dWr[r], a0);
                    a1 = fmaf(dbA[4 + r], dWr[4 + r], a1);
                    a2 = fmaf(dbA[8 + r], dWr[8 + r], a2);
                    a3 = fmaf(dbA[12 + r], dWr[12 + r], a3);
                }
                float acc = (a0 + a1) + (a2 + a3);
                float dtt = fmaxf(acc, 0.f) + __logf(1.f + __expf(-fabsf(acc)));
                float dtx = dtt * xv;
                float y0 = 0.f, y1 = 0.f, y2 = 0.f, y3 = 0.f;
#pragma unroll
                for (int s = 0; s < 4; s++) {
                    float dA0 = exp2f(dtt * ArowL2[s]);
                    float dA1 = exp2f(dtt * ArowL2[4 + s]);
                    float dA2 = exp2f(dtt * ArowL2[8 + s]);
                    float dA3 = exp2f(dtt * ArowL2[12 + s]);
                    h[s] = fmaf(dA0, h[s], dtx * dbA[16 + s]);
                    h[4 + s] = fmaf(dA1, h[4 + s], dtx * dbA[20 + s]);
                    h[8 + s] = fmaf(dA2, h[8 + s], dtx * dbA[24 + s]);
                    h[12 + s] = fmaf(dA3, h[12 + s], dtx * dbA[28 + s]);
                    y0 = fmaf(h[s], dbA[32 + s], y0);
                    y1 = fmaf(h[4 + s], dbA[36 + s], y1);
                    y2 = fmaf(h[8 + s], dbA[40 + s], y2);
                    y3 = fmaf(h[12 + s], dbA[44 + s], y3);
                }
                float y = (y0 + y1) + (y2 + y3);
                yp[(size_t)l * 512] = (y + xv * dsk) * (zv * fast_sig(zv));
            }
            const float4* nr2 = (const float4*)(dr + (size_t)(l + 2) * 48);
#pragma unroll
            for (int i = 0; i < 12; i++) ((float4*)dbA)[i] = nr2[i];
            float xv2 = xp[(size_t)(l + 2) * 512];
            float zv2 = zp[(size_t)(l + 2) * 1024];
            if (l + 1 < SEGLEN) {
                float a0 = dtbv, a1 = 0.f, a2 = 0.f, a3 = 0.f;
#pragma unroll
                for (int r = 0; r < 4; r++) {
                    a0 = fmaf(dbB[r], dWr[r], a0);
                    a1 = fmaf(dbB[4 + r], dWr[4 + r], a1);
                    a2 = fmaf(dbB[8 + r], dWr[8 + r], a2);
                    a3 = fmaf(dbB[12 + r], dWr[12 + r], a3);
                }
                float acc = (a0 + a1) + (a2 + a3);
                float dtt = fmaxf(acc, 0.f) + __logf(1.f + __expf(-fabsf(acc)));
                float dtx = dtt * xv1;
                float y0 = 0.f, y1 = 0.f, y2 = 0.f, y3 = 0.f;
#pragma unroll
                for (int s = 0; s < 4; s++) {
                    float dA0 = exp2f(dtt * ArowL2[s]);
                    float dA1 = exp2f(dtt * ArowL2[4 + s]);
                    float dA2 = exp2f(dtt * ArowL2[8 + s]);
                    float dA3 = exp2f(dtt * ArowL2[12 + s]);
                    h[s] = fmaf(dA0, h[s], dtx * dbB[16 + s]);
                    h[4 + s] = fmaf(dA1, h[4 + s], dtx * dbB[20 + s]);
                    h[8 + s] = fmaf(dA2, h[8 + s], dtx * dbB[24 + s]);
                    h[12 + s] = fmaf(dA3, h[12 + s], dtx * dbB[28 + s]);
                    y0 = fmaf(h[s], dbB[32 + s], y0);
                    y1 = fmaf(h[4 + s], dbB[36 + s], y1);
                    y2 = fmaf(h[8 + s], dbB[40 + s], y2);
                    y3 = fmaf(h[12 + s], dbB[44 + s], y3);
                }
                float y = (y0 + y1) + (y2 + y3);
                yp[(size_t)(l + 1) * 512] = (y + xv1 * dsk) * (zv1 * fast_sig(zv1));
            }
            xv = xv2; zv = zv2;
        }
    }
}

extern "C" void kernel_launch(void* const* d_in, const int* in_sizes, int n_in,
                              void* d_out, int out_size, void* d_ws, size_t ws_size,
                              hipStream_t stream) {
    const float* coords   = (const float*)d_in[0];
    const float* emb_W    = (const float*)d_in[1];
    const float* emb_b    = (const float*)d_in[2];
    const float* ln_w     = (const float*)d_in[3];
    const float* ln_b     = (const float*)d_in[4];
    const float* in_W     = (const float*)d_in[5];
    const float* conv_W   = (const float*)d_in[6];
    const float* conv_b   = (const float*)d_in[7];
    const float* xproj_W  = (const float*)d_in[8];
    const float* dtproj_W = (const float*)d_in[9];
    const float* dtproj_b = (const float*)d_in[10];
    const float* A_log    = (const float*)d_in[11];
    const float* D_skip   = (const float*)d_in[12];
    const float* out_W    = (const float*)d_in[13];
    const float* normf_w  = (const float*)d_in[14];
    const float* normf_b  = (const float*)d_in[15];
    const float* head_W   = (const float*)d_in[16];
    float* out = (float*)d_out;

    const int T = NTOK;  // 9600
    float* x     = (float*)d_ws;
    float* resid = x + (size_t)T * D_MODEL;
    float* h     = resid + (size_t)T * D_MODEL;
    float* xz    = h + (size_t)T * D_MODEL;
    float* xc    = xz + (size_t)T * 2 * D_INNER;   // conv output, then scan output (in place)
    float* dbl   = xc + (size_t)T * D_INNER;
    // note: region past dbl (former hseg) stays allocated; harmless prefetch over-reads land there

    embed_kernel<<<T, D_MODEL, 0, stream>>>(coords, emb_W, emb_b, x);

    for (int i = 0; i < N_LAYERS; i++) {
        ln_res_kernel<<<T, D_MODEL, 0, stream>>>(x, resid, h, ln_w + i * D_MODEL,
                                                 ln_b + i * D_MODEL, i == 0);
        // in_proj: (9600,256) x (1024,256)^T -> (9600,1024)
        gemm_mfma<128, 128, false><<<dim3(T / 128, 8), 256, 0, stream>>>(
            h, in_W + (size_t)i * 2 * D_INNER * D_MODEL, xz, 2 * D_INNER, D_MODEL);
        conv_silu_kernel<<<T * 128 / 256, 256, 0, stream>>>(
            xz, conv_W + i * D_INNER * D_CONV, conv_b + i * D_INNER, xc);
        // xproj: (9600,512) x (48,512)^T -> (9600,48)
        gemm_mfma<64, 64, true><<<dim3(T / 64, 1), 256, 0, stream>>>(
            xc, xproj_W + (size_t)i * 48 * D_INNER, dbl, 48, D_INNER);
        // single-kernel 3-phase scan, combine in LDS
        scan_block<<<dim3(8, BATCH), 768, 0, stream>>>(
            xc, dbl, xz, A_log + (size_t)i * D_INNER * D_STATE, D_skip + i * D_INNER,
            dtproj_W + (size_t)i * D_INNER * DT_RANK, dtproj_b + i * D_INNER, xc);
        // out_proj: (9600,512) x (256,512)^T -> (9600,256)
        gemm_mfma<64, 64, false><<<dim3(T / 64, 4), 256, 0, stream>>>(
            xc, out_W + (size_t)i * D_MODEL * D_INNER, x, D_MODEL, D_INNER);
    }

    final_rms_kernel<<<T, D_MODEL, 0, stream>>>(x, resid, normf_w, normf_b, h);
    // head: (9600,256) x (300,256)^T -> (9600,300)
    gemm_mfma<64, 64, true><<<dim3(T / 64, 5), 256, 0, stream>>>(
        h, head_W, out, CITY, D_MODEL);
}